// Round 4
// baseline (454.002 us; speedup 1.0000x reference)
//
#include <hip/hip_runtime.h>
#include <hip/hip_bf16.h>
#include <float.h>
#include <math.h>

#define Bz 8
#define Dd 256
#define Tt 2048
#define Kk 8192
#define Mm (Bz*Tt)          // 16384 rows (b*T + t)

// Scorer v12: NO LDS staging at all. k_pre's Ah/Bh are row-major (row,k), and
// the 16x16x32 f16 MFMA operand layout (lane l15 -> row, quad -> 8-elem
// k-chunk) makes every fragment a single aligned 16 B global load. K=256 is
// only 8 MFMA steps -> stream fragments through registers, zero K-loop
// barriers, waves fully independent. Block = 128 rows x 256 cols, 4 waves
// (2wy x 2wx), 2 blocks/CU. XCD-chunked swizzle with bx-OUTER inside each
// chunk: concurrent blocks on an XCD share one 128 KB B panel (L2-hot).
#define NSPL 32

#define ZG_CAP 4096
#define PAIR_CAP 131072     // candidate (row,code) pairs; expected ~6K

// Margin: covers f16 fast-pass score error + np fp32 quantization straddle
#define RESCAN_MARGIN 6e-4f

typedef __attribute__((ext_vector_type(8))) _Float16 f16x8;
typedef __attribute__((ext_vector_type(4))) float    f32x4;

// ---------------------------------------------------------------------------
// numpy-faithful pairwise sum of squares (blocksize-128 pairwise, 8 accums)
// ---------------------------------------------------------------------------
__device__ __forceinline__ float np_sumsq128(const float* __restrict__ x) {
  float r0 = __fmul_rn(x[0], x[0]);
  float r1 = __fmul_rn(x[1], x[1]);
  float r2 = __fmul_rn(x[2], x[2]);
  float r3 = __fmul_rn(x[3], x[3]);
  float r4 = __fmul_rn(x[4], x[4]);
  float r5 = __fmul_rn(x[5], x[5]);
  float r6 = __fmul_rn(x[6], x[6]);
  float r7 = __fmul_rn(x[7], x[7]);
  for (int i = 8; i < 128; i += 8) {
    r0 = __fadd_rn(r0, __fmul_rn(x[i+0], x[i+0]));
    r1 = __fadd_rn(r1, __fmul_rn(x[i+1], x[i+1]));
    r2 = __fadd_rn(r2, __fmul_rn(x[i+2], x[i+2]));
    r3 = __fadd_rn(r3, __fmul_rn(x[i+3], x[i+3]));
    r4 = __fadd_rn(r4, __fmul_rn(x[i+4], x[i+4]));
    r5 = __fadd_rn(r5, __fmul_rn(x[i+5], x[i+5]));
    r6 = __fadd_rn(r6, __fmul_rn(x[i+6], x[i+6]));
    r7 = __fadd_rn(r7, __fmul_rn(x[i+7], x[i+7]));
  }
  return __fadd_rn(__fadd_rn(__fadd_rn(r0, r1), __fadd_rn(r2, r3)),
                   __fadd_rn(__fadd_rn(r4, r5), __fadd_rn(r6, r7)));
}
__device__ __forceinline__ float np_sumsq256(const float* __restrict__ x) {
  return __fadd_rn(np_sumsq128(x), np_sumsq128(x + 128));
}

// ---------------------------------------------------------------------------
// k_pre: fused [cast_z | cast_cb | prep] by blockIdx range (fewer launches)
// ---------------------------------------------------------------------------
__global__ void k_pre(const float* __restrict__ z, const float* __restrict__ cb,
                      _Float16* __restrict__ Ah, _Float16* __restrict__ Bh,
                      float* __restrict__ sc,
                      double* __restrict__ loss_accum, int* __restrict__ rc) {
  const int bid = blockIdx.x;
  const int tid = threadIdx.x;
  if (bid < 1024) {
    // ---- transpose-cast z (B,D,T) f32 -> Ah (M,D) f16
    __shared__ _Float16 tile[64][64 + 8];
    const int b  = bid >> 7;
    const int dt = (bid >> 5) & 3;
    const int tt = bid & 31;
    const int d0 = dt * 64, t0 = tt * 64;
    const float* zb = z + ((size_t)b * Dd + d0) * Tt + t0;
    #pragma unroll
    for (int p = 0; p < 4; ++p) {
      const int d  = p * 16 + (tid >> 4);
      const int tl = (tid & 15) * 4;
      const float4 v = *(const float4*)(zb + (size_t)d * Tt + tl);
      tile[tl+0][d] = (_Float16)v.x;
      tile[tl+1][d] = (_Float16)v.y;
      tile[tl+2][d] = (_Float16)v.z;
      tile[tl+3][d] = (_Float16)v.w;
    }
    __syncthreads();
    const int r = tid >> 2, seg = tid & 3;
    const int m = b * Tt + t0 + r;
    int4* dst = (int4*)(Ah + (size_t)m * Dd + d0 + seg * 16);
    const int4* srcv = (const int4*)(&tile[r][seg * 16]);
    dst[0] = srcv[0];
    dst[1] = srcv[1];
  } else if (bid < 2048) {
    // ---- cast codebook f32 -> f16, prescaled by 256
    const size_t g = (size_t)(bid - 1024) * 256 + tid;
    const float4 v0 = *(const float4*)(cb + g * 8);
    const float4 v1 = *(const float4*)(cb + g * 8 + 4);
    f16x8 o;
    o[0] = (_Float16)(v0.x * 256.f); o[1] = (_Float16)(v0.y * 256.f);
    o[2] = (_Float16)(v0.z * 256.f); o[3] = (_Float16)(v0.w * 256.f);
    o[4] = (_Float16)(v1.x * 256.f); o[5] = (_Float16)(v1.y * 256.f);
    o[6] = (_Float16)(v1.z * 256.f); o[7] = (_Float16)(v1.w * 256.f);
    *(f16x8*)(Bh + g * 8) = o;
  } else {
    // ---- np-faithful codebook norms (8 lanes own np's 8 acc chains)
    if (bid == 2048 && tid == 0) {
      *loss_accum = 0.0; rc[0] = 0; rc[1] = 0; rc[2] = 0;
    }
    const int gid = (bid - 2048) * 256 + tid;
    const int lane = gid & 63;
    const int j = lane & 7, sub = lane >> 3;
    const int row = (gid >> 6) * 8 + sub;
    if (row >= Kk) return;
    const float* x = cb + (size_t)row * Dd;
    float c0 = __fmul_rn(x[j], x[j]);
    float c1 = __fmul_rn(x[128 + j], x[128 + j]);
    #pragma unroll
    for (int i = 8; i < 128; i += 8) {
      c0 = __fadd_rn(c0, __fmul_rn(x[j + i], x[j + i]));
      c1 = __fadd_rn(c1, __fmul_rn(x[128 + j + i], x[128 + j + i]));
    }
    #pragma unroll
    for (int off = 1; off <= 4; off <<= 1) {
      c0 = __fadd_rn(c0, __shfl_xor(c0, off));
      c1 = __fadd_rn(c1, __shfl_xor(c1, off));
    }
    if (j == 0) sc[row] = __fadd_rn(c0, c1);
  }
}

// ---------------------------------------------------------------------------
// f16 MFMA score pass v12: direct global->register fragments, no LDS staging
// ---------------------------------------------------------------------------
__global__ __launch_bounds__(256, 2)
void k_mfma(const _Float16* __restrict__ Ah, const _Float16* __restrict__ Bh,
            const float* __restrict__ sc,
            float* __restrict__ pd1, float* __restrict__ pd2, int* __restrict__ pi1) {
  __shared__ float mr1[256];
  __shared__ float mr2[256];
  __shared__ int   mri[256];

  const int tid  = threadIdx.x;
  // XCD-chunked bijective swizzle (nwg=4096, %8==0): physical b -> XCD b%8;
  // XCD x gets logical chunk [x*512,(x+1)*512). Inside the chunk bx is OUTER
  // (bid>>7) so ~64 concurrent blocks on an XCD share ONE 128 KB B panel.
  const int bid  = ((blockIdx.x & 7) << 9) + (blockIdx.x >> 3);
  const int bx   = bid >> 7;             // 32 n-tiles of 256 cols
  const int by   = bid & 127;            // 128 m-tiles of 128 rows
  const int m0   = by * 128, n0 = bx * 256;
  const int w    = tid >> 6, lane = tid & 63;
  const int wy   = w >> 1, wx = w & 1;   // 2 row-bands x 2 col-halves
  const int l15  = lane & 15, quad = lane >> 4;

  // per-lane fragment bases (row-major (row,k) f16, 16 B per fragment)
  const _Float16* __restrict__ Ab = Ah + ((size_t)(m0 + wy * 64 + l15)) * Dd + quad * 8;
  const _Float16* __restrict__ Bb = Bh + ((size_t)(n0 + wx * 64 + l15)) * Dd + quad * 8;

  f32x4 acc[2][4][4];
  #pragma unroll
  for (int nt = 0; nt < 2; ++nt)
    #pragma unroll
    for (int mi = 0; mi < 4; ++mi)
      #pragma unroll
      for (int ni = 0; ni < 4; ++ni)
        acc[nt][mi][ni] = (f32x4){0.f, 0.f, 0.f, 0.f};

  // ---- K loop: 8 steps of {12 global 16 B loads, 32 MFMA}; no barriers.
  //      Accumulation order per acc element is (kc,ks) ascending == v11.
  #pragma unroll
  for (int kc = 0; kc < 4; ++kc) {
    #pragma unroll
    for (int ks = 0; ks < 2; ++ks) {
      const int ko = kc * 64 + ks * 32;  // element offset within the row
      f16x8 af[4], bf[2][4];
      #pragma unroll
      for (int mi = 0; mi < 4; ++mi)
        af[mi] = *(const f16x8*)(Ab + (size_t)mi * 16 * Dd + ko);
      #pragma unroll
      for (int nt = 0; nt < 2; ++nt)
        #pragma unroll
        for (int ni = 0; ni < 4; ++ni)
          bf[nt][ni] = *(const f16x8*)(Bb + (size_t)(nt * 128 + ni * 16) * Dd + ko);
      #pragma unroll
      for (int nt = 0; nt < 2; ++nt)
        #pragma unroll
        for (int mi = 0; mi < 4; ++mi)
          #pragma unroll
          for (int ni = 0; ni < 4; ++ni)
            acc[nt][mi][ni] = __builtin_amdgcn_mfma_f32_16x16x32_f16(
                af[mi], bf[nt][ni], acc[nt][mi][ni], 0, 0, 0);
    }
  }

  // ---- epilogue (once per block): per-row top-2 over all 256 cols
  float scv[2][4];
  #pragma unroll
  for (int nt = 0; nt < 2; ++nt)
    #pragma unroll
    for (int ni = 0; ni < 4; ++ni)
      scv[nt][ni] = sc[n0 + nt * 128 + wx * 64 + ni * 16 + l15];

  float s1[16], s2[16]; int i1[16];
  #pragma unroll
  for (int mi = 0; mi < 4; ++mi)
    #pragma unroll
    for (int r = 0; r < 4; ++r) {
      const int q = mi * 4 + r;
      float a1 = INFINITY, a2 = INFINITY; int ai = 0x7fffffff;
      #pragma unroll
      for (int nt = 0; nt < 2; ++nt)
        #pragma unroll
        for (int ni = 0; ni < 4; ++ni) {       // (nt,ni) ascending -> k ascending
          const float sv = fmaf(-0.0078125f, acc[nt][mi][ni][r], scv[nt][ni]);  // -2/256
          const int   k  = n0 + nt * 128 + wx * 64 + ni * 16 + l15;
          if (sv < a1) { a2 = a1; a1 = sv; ai = k; }
          else if (sv < a2) a2 = sv;
        }
      s1[q] = a1; s2[q] = a2; i1[q] = ai;
    }

  #pragma unroll
  for (int off = 1; off <= 8; off <<= 1)
    #pragma unroll
    for (int q = 0; q < 16; ++q) {
      const float o1 = __shfl_xor(s1[q], off);
      const float o2 = __shfl_xor(s2[q], off);
      const int   oi = __shfl_xor(i1[q], off);
      const float n2 = fminf(fminf(s2[q], o2), fmaxf(s1[q], o1));
      if (o1 < s1[q] || (o1 == s1[q] && oi < i1[q])) { s1[q] = o1; i1[q] = oi; }
      s2[q] = n2;
    }

  __syncthreads();
  if (l15 == 0) {
    #pragma unroll
    for (int mi = 0; mi < 4; ++mi)
      #pragma unroll
      for (int r = 0; r < 4; ++r) {
        const int q  = mi * 4 + r;
        const int ml = wy * 64 + mi * 16 + quad * 4 + r;   // 0..127
        mr1[ml * 2 + wx] = s1[q];
        mr2[ml * 2 + wx] = s2[q];
        mri[ml * 2 + wx] = i1[q];
      }
  }
  __syncthreads();
  if (tid < 128) {
    float a1 = mr1[tid * 2], a2 = mr2[tid * 2]; int ai = mri[tid * 2];
    const float b1 = mr1[tid * 2 + 1], b2 = mr2[tid * 2 + 1];
    const int   bi = mri[tid * 2 + 1];
    if (b1 < a1 || (b1 == a1 && bi < ai)) { a2 = fminf(a1, b2); a1 = b1; ai = bi; }
    else a2 = fminf(a2, b1);
    const size_t o = (size_t)bx * Mm + (size_t)(m0 + tid);  // split = 256-col window
    pd1[o] = a1; pd2[o] = a2; pi1[o] = ai;
  }
}

// ---------------------------------------------------------------------------
// combine the NSPL partials per row; flag near-ties and emit candidate pairs.
// A code can only be the true argmin if its fast score <= a1 + MARGIN (same
// eps <= MARGIN/2 assumption as the gap test). Splits with s1 <= thr give
// their winner; splits with s2 <= thr (rare) need all 256 codes enumerated.
// ---------------------------------------------------------------------------
__global__ void k_combine(const float* __restrict__ pd1, const float* __restrict__ pd2,
                          const int* __restrict__ pi1, int* __restrict__ idxf,
                          int* __restrict__ rc, int* __restrict__ rlist,
                          int* __restrict__ pairs, int* __restrict__ slist,
                          float* __restrict__ outIdx) {
  const int m = blockIdx.x * blockDim.x + threadIdx.x;
  if (m >= Mm) return;
  float a1 = INFINITY, a2 = INFINITY; int ai = 0x7fffffff;
  for (int spl = 0; spl < NSPL; ++spl) {         // spl ascending -> k ascending
    const size_t o = (size_t)spl * Mm + m;
    const float b1 = pd1[o], b2 = pd2[o]; const int bi = pi1[o];
    if (b1 < a1 || (b1 == a1 && bi < ai)) { a2 = fminf(a1, b2); a1 = b1; ai = bi; }
    else a2 = fminf(a2, b1);
  }
  idxf[m]   = ai;
  outIdx[m] = (float)ai;
  if (a2 - a1 <= RESCAN_MARGIN) {
    const int p = atomicAdd(&rc[0], 1);
    if (p < ZG_CAP) {
      rlist[p] = m;
      const float thr = a1 + RESCAN_MARGIN;
      // pass 1: count candidates
      int nc = 0;
      for (int spl = 0; spl < NSPL; ++spl) {
        const size_t o = (size_t)spl * Mm + m;
        if (pd2[o] <= thr) nc += 256;
        else if (pd1[o] <= thr) ++nc;
      }
      const int base = atomicAdd(&rc[1], nc);
      if (base + nc <= PAIR_CAP) {
        int wp = base;
        for (int spl = 0; spl < NSPL; ++spl) {
          const size_t o = (size_t)spl * Mm + m;
          const float b1 = pd1[o], b2 = pd2[o];
          if (b2 <= thr) {
            const int k0 = spl * 256;
            for (int c = 0; c < 256; ++c) pairs[wp++] = (p << 13) | (k0 + c);
          } else if (b1 <= thr) {
            pairs[wp++] = (p << 13) | pi1[o];
          }
        }
      } else {
        // overflow: sentinel-fill our in-range slice (no holes), divert to slow
        for (int q = base; q < PAIR_CAP; ++q) pairs[q] = -1;
        const int s = atomicAdd(&rc[2], 1); slist[s] = m;
      }
    } else {
      // zg overflow: full slow scan for this row
      const int s = atomicAdd(&rc[2], 1); slist[s] = m;
    }
  }
}

// ---------------------------------------------------------------------------
// gather flagged rows into compact zg; np norms; init packed minima
// ---------------------------------------------------------------------------
__global__ void k_gather(const float* __restrict__ z, const int* __restrict__ rc,
                         const int* __restrict__ rlist, float* __restrict__ zg,
                         float* __restrict__ Ag, unsigned long long* __restrict__ pbrow) {
  __shared__ float zr[Dd];
  const int cnt = min(rc[0], ZG_CAP);
  for (int it = blockIdx.x; it < cnt; it += gridDim.x) {
    const int m = rlist[it];
    const int b = m / Tt, t = m & (Tt - 1);
    __syncthreads();
    zr[threadIdx.x] = z[(size_t)b * Dd * Tt + (size_t)threadIdx.x * Tt + t];
    __syncthreads();
    zg[(size_t)it * Dd + threadIdx.x] = zr[threadIdx.x];
    if (threadIdx.x == 0) { Ag[it] = np_sumsq256(zr); pbrow[it] = ~0ull; }
  }
}

// ---------------------------------------------------------------------------
// candidate-pair exact rescan: one thread per (row,code) pair; np-faithful
// fp64 dot (same segment grouping / rounding sequence as the full scan),
// packed (orderable f32, idx) atomicMin per row.
// ---------------------------------------------------------------------------
__global__ __launch_bounds__(256)
void k_rescan_pairs(const float* __restrict__ cb, const float* __restrict__ sc,
                    const int* __restrict__ rc, const float* __restrict__ zg,
                    const float* __restrict__ Ag,
                    const int* __restrict__ pairs,
                    unsigned long long* __restrict__ pbrow) {
  const int n = min(rc[1], PAIR_CAP);
  const int i = blockIdx.x * 256 + threadIdx.x;
  if (i >= n) return;
  const int pr = pairs[i];
  if (pr < 0) return;                            // overflow sentinel
  const int it = pr >> 13, k = pr & (Kk - 1);
  const float* __restrict__ zp = zg + (size_t)it * Dd;
  const float* __restrict__ cp = cb + (size_t)k * Dd;
  double M8 = 0.0;
  #pragma unroll
  for (int sg = 0; sg < 8; ++sg) {
    double a0 = 0.0, a1 = 0.0, a2 = 0.0, a3 = 0.0;
    #pragma unroll
    for (int j = 0; j < 32; j += 4) {
      const float4 c4 = *(const float4*)(cp + sg * 32 + j);
      const float4 z4 = *(const float4*)(zp + sg * 32 + j);
      a0 = fma((double)c4.x, (double)z4.x, a0);
      a1 = fma((double)c4.y, (double)z4.y, a1);
      a2 = fma((double)c4.z, (double)z4.z, a2);
      a3 = fma((double)c4.w, (double)z4.w, a3);
    }
    M8 += (a0 + a1) + (a2 + a3);
  }
  const float M  = (float)M8;
  const float t1 = __fsub_rn(Ag[it], __fmul_rn(2.0f, M));
  const float dq = __fadd_rn(t1, sc[k]);
  unsigned int fb = __float_as_uint(dq);
  fb = (fb & 0x80000000u) ? ~fb : (fb | 0x80000000u);
  const unsigned long long pack = ((unsigned long long)fb << 32) | (unsigned)k;
  atomicMin(pbrow + it, pack);
}

__global__ void k_rescan_final(const int* __restrict__ rc, const int* __restrict__ rlist,
                               const unsigned long long* __restrict__ pbrow,
                               int* __restrict__ idxf, float* __restrict__ outIdx) {
  const int cnt = min(rc[0], ZG_CAP);
  const int it = blockIdx.x * blockDim.x + threadIdx.x;
  if (it < cnt) {
    const unsigned long long pb = pbrow[it];
    if (pb != ~0ull) {                           // untouched => slow-path row
      const int idx = (int)(unsigned)(pb & 0xFFFFFFFFull);
      const int m = rlist[it];
      idxf[m] = idx; outIdx[m] = (float)idx;
    }
  }
}

// overflow fallback: normally 0 iterations
__global__ void k_rescan_slow(const float* __restrict__ z, const float* __restrict__ cb,
                              const float* __restrict__ sc,
                              const int* __restrict__ rc, const int* __restrict__ slist,
                              int* __restrict__ idxf, float* __restrict__ outIdx) {
  __shared__ float zrow[Dd];
  __shared__ float Ash;
  __shared__ float sval[256];
  __shared__ int   sidx[256];
  const int tid = threadIdx.x;
  const int cnt = rc[2];
  for (int it = blockIdx.x; it < cnt; it += gridDim.x) {
    const int m = slist[it];
    const int b = m / Tt, t = m & (Tt - 1);
    __syncthreads();
    zrow[tid] = z[(size_t)b * Dd * Tt + (size_t)tid * Tt + t];
    __syncthreads();
    if (tid == 0) Ash = np_sumsq256(zrow);
    __syncthreads();
    const float A = Ash;
    float best = INFINITY; int bi = 0x7fffffff;
    for (int k = tid; k < Kk; k += 256) {
      const float* cr = cb + (size_t)k * Dd;
      double a0 = 0.0, a1 = 0.0, a2 = 0.0, a3 = 0.0;
      for (int d = 0; d < Dd; d += 4) {
        const float4 c4 = *(const float4*)(cr + d);
        a0 = fma((double)c4.x, (double)zrow[d+0], a0);
        a1 = fma((double)c4.y, (double)zrow[d+1], a1);
        a2 = fma((double)c4.z, (double)zrow[d+2], a2);
        a3 = fma((double)c4.w, (double)zrow[d+3], a3);
      }
      const float M  = (float)((a0 + a1) + (a2 + a3));
      const float t1 = __fsub_rn(A, __fmul_rn(2.0f, M));
      const float dq = __fadd_rn(t1, sc[k]);
      if (dq < best) { best = dq; bi = k; }
    }
    sval[tid] = best; sidx[tid] = bi;
    __syncthreads();
    for (int off = 128; off; off >>= 1) {
      if (tid < off) {
        if (sval[tid+off] < sval[tid] ||
            (sval[tid+off] == sval[tid] && sidx[tid+off] < sidx[tid])) {
          sval[tid] = sval[tid+off]; sidx[tid] = sidx[tid+off];
        }
      }
      __syncthreads();
    }
    if (tid == 0) { idxf[m] = sidx[0]; outIdx[m] = (float)sidx[0]; }
    __syncthreads();
  }
}

// ---------------------------------------------------------------------------
// fused gather + transpose + STE + loss: out[b][d][t] = z + (cb[idx] - z)
// ---------------------------------------------------------------------------
__global__ void k_out(const float* __restrict__ z, const float* __restrict__ cb,
                      const int* __restrict__ idxf,
                      float* __restrict__ outZ, double* __restrict__ loss_accum) {
  __shared__ float tile[64][65];          // [d][t]
  const int tid = threadIdx.x;
  const int bidx = blockIdx.x;            // 8 * 4 * 32 = 1024
  const int b  = bidx >> 7;
  const int dt = (bidx >> 5) & 3;
  const int tt = bidx & 31;
  const int d0 = dt * 64, t0 = tt * 64;
  {
    const int r = tid >> 2, seg = tid & 3;
    const int idx = idxf[b * Tt + t0 + r];
    const float* src = cb + (size_t)idx * Dd + d0 + seg * 16;
    #pragma unroll
    for (int q4 = 0; q4 < 4; ++q4) {
      const float4 v = *(const float4*)(src + q4 * 4);
      tile[seg * 16 + q4 * 4 + 0][r] = v.x;
      tile[seg * 16 + q4 * 4 + 1][r] = v.y;
      tile[seg * 16 + q4 * 4 + 2][r] = v.z;
      tile[seg * 16 + q4 * 4 + 3][r] = v.w;
    }
  }
  __syncthreads();
  const float* zbase = z + ((size_t)b * Dd + d0) * Tt + t0;
  float*       obase = outZ + ((size_t)b * Dd + d0) * Tt + t0;
  double ls = 0.0;
  #pragma unroll
  for (int p = 0; p < 4; ++p) {
    const int d  = p * 16 + (tid >> 4);
    const int t4 = (tid & 15) * 4;
    const float4 zv = *(const float4*)(zbase + (size_t)d * Tt + t4);
    const float q0 = tile[d][t4+0], q1 = tile[d][t4+1];
    const float q2 = tile[d][t4+2], q3 = tile[d][t4+3];
    const float r0 = q0 - zv.x, r1 = q1 - zv.y, r2 = q2 - zv.z, r3 = q3 - zv.w;
    float4 o;
    o.x = zv.x + r0; o.y = zv.y + r1; o.z = zv.z + r2; o.w = zv.w + r3;
    *(float4*)(obase + (size_t)d * Tt + t4) = o;
    ls += (double)r0*r0 + (double)r1*r1 + (double)r2*r2 + (double)r3*r3;
  }
  #pragma unroll
  for (int off = 32; off; off >>= 1) ls += __shfl_down(ls, off);
  if ((tid & 63) == 0) atomicAdd(loss_accum, ls);
}

__global__ void k_finalize(const double* __restrict__ loss_accum, float* __restrict__ outLoss) {
  const double mean = *loss_accum / (double)((size_t)Bz * Dd * Tt);
  *outLoss = (float)(mean + 0.1 * mean);
}

// ---------------------------------------------------------------------------
extern "C" void kernel_launch(void* const* d_in, const int* in_sizes, int n_in,
                              void* d_out, int out_size, void* d_ws, size_t ws_size,
                              hipStream_t stream) {
  (void)in_sizes; (void)n_in; (void)out_size; (void)ws_size;
  const float* z  = (const float*)d_in[0];   // (B, D, T) fp32
  const float* cb = (const float*)d_in[1];   // (K, D)    fp32

  float* outZ    = (float*)d_out;
  float* outIdx  = outZ + (size_t)Bz * Dd * Tt;
  float* outLoss = outIdx + Mm;

  char* w = (char*)d_ws;
  double*    loss_accum = (double*)w;    w += 16;
  int*       rc         = (int*)w;       w += 16;   // [0]=rows [1]=pairs [2]=slow
  int*       rlist      = (int*)w;       w += sizeof(int)   * Mm;
  int*       slist      = (int*)w;       w += sizeof(int)   * Mm;
  int*       idxf       = (int*)w;       w += sizeof(int)   * Mm;
  float*     sc         = (float*)w;     w += sizeof(float) * Kk;
  _Float16*  Ah         = (_Float16*)w;  w += sizeof(_Float16) * (size_t)Mm * Dd;
  _Float16*  Bh         = (_Float16*)w;  w += sizeof(_Float16) * (size_t)Kk * Dd;
  float*     zg         = (float*)w;     w += sizeof(float) * (size_t)ZG_CAP * Dd;
  float*     Ag         = (float*)w;     w += sizeof(float) * ZG_CAP;
  unsigned long long* pbrow = (unsigned long long*)w; w += sizeof(unsigned long long) * ZG_CAP;
  int*       pairs      = (int*)w;       w += sizeof(int) * PAIR_CAP;
  float*     pd1        = (float*)w;     w += sizeof(float) * (size_t)NSPL * Mm;
  float*     pd2        = (float*)w;     w += sizeof(float) * (size_t)NSPL * Mm;
  int*       pi1        = (int*)w;       /* total ~25 MB */

  k_pre         <<<dim3(2304), 256, 0, stream>>>(z, cb, Ah, Bh, sc, loss_accum, rc);
  k_mfma        <<<dim3((Mm / 128) * (Kk / 256)), 256, 0, stream>>>(Ah, Bh, sc, pd1, pd2, pi1);
  k_combine     <<<dim3(Mm / 256), 256, 0, stream>>>(pd1, pd2, pi1, idxf, rc, rlist, pairs, slist, outIdx);
  k_gather      <<<dim3(256), 256, 0, stream>>>(z, rc, rlist, zg, Ag, pbrow);
  k_rescan_pairs<<<dim3(PAIR_CAP / 256), 256, 0, stream>>>(cb, sc, rc, zg, Ag, pairs, pbrow);
  k_rescan_slow <<<dim3(64), 256, 0, stream>>>(z, cb, sc, rc, slist, idxf, outIdx);
  k_rescan_final<<<dim3(ZG_CAP / 256), 256, 0, stream>>>(rc, rlist, pbrow, idxf, outIdx);
  k_out         <<<dim3(1024), 256, 0, stream>>>(z, cb, idxf, outZ, loss_accum);
  k_finalize    <<<dim3(1), 1, 0, stream>>>(loss_accum, outLoss);
}

// Round 5
// 372.326 us; speedup vs baseline: 1.2194x; 1.2194x over previous
//
#include <hip/hip_runtime.h>
#include <hip/hip_bf16.h>
#include <float.h>
#include <math.h>

#define Bz 8
#define Dd 256
#define Tt 2048
#define Kk 8192
#define Mm (Bz*Tt)          // 16384 rows (b*T + t)

// Scorer v13: 256x256 tile, 512 thr (8 waves, 4wy x 2wx), double-buffered
// LDS (As[2]/Bs[2]) with T3/T4 schedule: raw s_barrier + COUNTED
// s_waitcnt vmcnt(8) so the prefetched kc stays in flight ACROSS the
// barrier (v11's __syncthreads drained vmcnt(0) and nullified the dbuf).
// XCD swizzle: chunk = 4 bx-panels x all by -> 512 KB B L2-resident/XCD.
#define NSPL 32

#define ZG_CAP 4096
#define PAIR_CAP 131072     // candidate (row,code) pairs; expected ~6K

// Margin: covers f16 fast-pass score error + np fp32 quantization straddle
#define RESCAN_MARGIN 6e-4f

typedef __attribute__((ext_vector_type(8))) _Float16 f16x8;
typedef __attribute__((ext_vector_type(4))) float    f32x4;

// async global->LDS DMA, 16 B per lane; lds dest = wave-uniform base + lane*16
__device__ __forceinline__ void gld16(const void* g, void* l) {
  __builtin_amdgcn_global_load_lds(
      (const __attribute__((address_space(1))) void*)g,
      (__attribute__((address_space(3))) void*)l, 16, 0, 0);
}

// raw barrier with compiler fences (no implicit vmcnt(0) drain)
__device__ __forceinline__ void bar() {
  __builtin_amdgcn_sched_barrier(0);
  asm volatile("" ::: "memory");
  __builtin_amdgcn_s_barrier();
  __builtin_amdgcn_sched_barrier(0);
}

// ---------------------------------------------------------------------------
// numpy-faithful pairwise sum of squares (blocksize-128 pairwise, 8 accums)
// ---------------------------------------------------------------------------
__device__ __forceinline__ float np_sumsq128(const float* __restrict__ x) {
  float r0 = __fmul_rn(x[0], x[0]);
  float r1 = __fmul_rn(x[1], x[1]);
  float r2 = __fmul_rn(x[2], x[2]);
  float r3 = __fmul_rn(x[3], x[3]);
  float r4 = __fmul_rn(x[4], x[4]);
  float r5 = __fmul_rn(x[5], x[5]);
  float r6 = __fmul_rn(x[6], x[6]);
  float r7 = __fmul_rn(x[7], x[7]);
  for (int i = 8; i < 128; i += 8) {
    r0 = __fadd_rn(r0, __fmul_rn(x[i+0], x[i+0]));
    r1 = __fadd_rn(r1, __fmul_rn(x[i+1], x[i+1]));
    r2 = __fadd_rn(r2, __fmul_rn(x[i+2], x[i+2]));
    r3 = __fadd_rn(r3, __fmul_rn(x[i+3], x[i+3]));
    r4 = __fadd_rn(r4, __fmul_rn(x[i+4], x[i+4]));
    r5 = __fadd_rn(r5, __fmul_rn(x[i+5], x[i+5]));
    r6 = __fadd_rn(r6, __fmul_rn(x[i+6], x[i+6]));
    r7 = __fadd_rn(r7, __fmul_rn(x[i+7], x[i+7]));
  }
  return __fadd_rn(__fadd_rn(__fadd_rn(r0, r1), __fadd_rn(r2, r3)),
                   __fadd_rn(__fadd_rn(r4, r5), __fadd_rn(r6, r7)));
}
__device__ __forceinline__ float np_sumsq256(const float* __restrict__ x) {
  return __fadd_rn(np_sumsq128(x), np_sumsq128(x + 128));
}

// ---------------------------------------------------------------------------
// k_pre: fused [cast_z | cast_cb | prep] by blockIdx range (fewer launches)
// ---------------------------------------------------------------------------
__global__ void k_pre(const float* __restrict__ z, const float* __restrict__ cb,
                      _Float16* __restrict__ Ah, _Float16* __restrict__ Bh,
                      float* __restrict__ sc,
                      double* __restrict__ loss_accum, int* __restrict__ rc) {
  const int bid = blockIdx.x;
  const int tid = threadIdx.x;
  if (bid < 1024) {
    // ---- transpose-cast z (B,D,T) f32 -> Ah (M,D) f16
    __shared__ _Float16 tile[64][64 + 8];
    const int b  = bid >> 7;
    const int dt = (bid >> 5) & 3;
    const int tt = bid & 31;
    const int d0 = dt * 64, t0 = tt * 64;
    const float* zb = z + ((size_t)b * Dd + d0) * Tt + t0;
    #pragma unroll
    for (int p = 0; p < 4; ++p) {
      const int d  = p * 16 + (tid >> 4);
      const int tl = (tid & 15) * 4;
      const float4 v = *(const float4*)(zb + (size_t)d * Tt + tl);
      tile[tl+0][d] = (_Float16)v.x;
      tile[tl+1][d] = (_Float16)v.y;
      tile[tl+2][d] = (_Float16)v.z;
      tile[tl+3][d] = (_Float16)v.w;
    }
    __syncthreads();
    const int r = tid >> 2, seg = tid & 3;
    const int m = b * Tt + t0 + r;
    int4* dst = (int4*)(Ah + (size_t)m * Dd + d0 + seg * 16);
    const int4* srcv = (const int4*)(&tile[r][seg * 16]);
    dst[0] = srcv[0];
    dst[1] = srcv[1];
  } else if (bid < 2048) {
    // ---- cast codebook f32 -> f16, prescaled by 256
    const size_t g = (size_t)(bid - 1024) * 256 + tid;
    const float4 v0 = *(const float4*)(cb + g * 8);
    const float4 v1 = *(const float4*)(cb + g * 8 + 4);
    f16x8 o;
    o[0] = (_Float16)(v0.x * 256.f); o[1] = (_Float16)(v0.y * 256.f);
    o[2] = (_Float16)(v0.z * 256.f); o[3] = (_Float16)(v0.w * 256.f);
    o[4] = (_Float16)(v1.x * 256.f); o[5] = (_Float16)(v1.y * 256.f);
    o[6] = (_Float16)(v1.z * 256.f); o[7] = (_Float16)(v1.w * 256.f);
    *(f16x8*)(Bh + g * 8) = o;
  } else {
    // ---- np-faithful codebook norms (8 lanes own np's 8 acc chains)
    if (bid == 2048 && tid == 0) {
      *loss_accum = 0.0; rc[0] = 0; rc[1] = 0; rc[2] = 0;
    }
    const int gid = (bid - 2048) * 256 + tid;
    const int lane = gid & 63;
    const int j = lane & 7, sub = lane >> 3;
    const int row = (gid >> 6) * 8 + sub;
    if (row >= Kk) return;
    const float* x = cb + (size_t)row * Dd;
    float c0 = __fmul_rn(x[j], x[j]);
    float c1 = __fmul_rn(x[128 + j], x[128 + j]);
    #pragma unroll
    for (int i = 8; i < 128; i += 8) {
      c0 = __fadd_rn(c0, __fmul_rn(x[j + i], x[j + i]));
      c1 = __fadd_rn(c1, __fmul_rn(x[128 + j + i], x[128 + j + i]));
    }
    #pragma unroll
    for (int off = 1; off <= 4; off <<= 1) {
      c0 = __fadd_rn(c0, __shfl_xor(c0, off));
      c1 = __fadd_rn(c1, __shfl_xor(c1, off));
    }
    if (j == 0) sc[row] = __fadd_rn(c0, c1);
  }
}

// ---------------------------------------------------------------------------
// f16 MFMA score pass v13 (256x256, dbuf, counted-vmcnt pipeline)
// ---------------------------------------------------------------------------
__global__ __launch_bounds__(512, 2)
void k_mfma(const _Float16* __restrict__ Ah, const _Float16* __restrict__ Bh,
            const float* __restrict__ sc,
            float* __restrict__ pd1, float* __restrict__ pd2, int* __restrict__ pi1) {
  __shared__ __align__(16) _Float16 As0[256 * 64];   // 32 KB
  __shared__ __align__(16) _Float16 As1[256 * 64];
  __shared__ __align__(16) _Float16 Bs0[256 * 64];
  __shared__ __align__(16) _Float16 Bs1[256 * 64];
  __shared__ float mr1[512];
  __shared__ float mr2[512];
  __shared__ int   mri[512];

  const int tid  = threadIdx.x;
  // XCD-chunked bijective swizzle (nwg=2048, %8==0): physical b -> XCD b%8;
  // XCD x owns logical [x*256,(x+1)*256) = 4 bx-panels x all 64 by.
  // B working set per XCD = 4 x 128 KB (L2-resident); A streams via L3.
  const int lg   = ((blockIdx.x & 7) << 8) + (blockIdx.x >> 3);
  const int bx   = lg >> 6;              // 32 n-tiles of 256 cols
  const int by   = lg & 63;              // 64 m-tiles of 256 rows
  const int m0   = by * 256, n0 = bx * 256;
  const int w    = tid >> 6, lane = tid & 63;
  const int wy   = w >> 1, wx = w & 1;   // 4 row-bands x 2 col-halves
  const int l15  = lane & 15, quad = lane >> 4;
  const int lhi  = lane >> 3, llo = lane & 7;   // staging roles
  const int p    = llo ^ lhi;                   // swizzled source chunk
  const int sw   = l15 & 7;                     // read-side swizzle key

  f32x4 acc[2][4][4];
  #pragma unroll
  for (int nt = 0; nt < 2; ++nt)
    #pragma unroll
    for (int mi = 0; mi < 4; ++mi)
      #pragma unroll
      for (int ni = 0; ni < 4; ++ni)
        acc[nt][mi][ni] = (f32x4){0.f, 0.f, 0.f, 0.f};

// stage one kc slice (A: 256 rows, B: 256 cols; 64 k): 8 gld16 per thread
#define STAGE(kc, As_, Bs_) do {                                             \
    _Pragma("unroll")                                                        \
    for (int c4 = 0; c4 < 4; ++c4) {                                         \
      const int c  = w * 4 + c4;                                             \
      const int r8 = c * 8 + lhi;                                            \
      gld16(Ah + (size_t)(m0 + r8) * Dd + (kc) * 64 + p * 8, As_ + c * 512); \
      gld16(Bh + (size_t)(n0 + r8) * Dd + (kc) * 64 + p * 8, Bs_ + c * 512); \
    } } while (0)

// ds_read + MFMA one kc slice (accumulation order identical to v10/v11)
#define COMPUTE(As_, Bs_) do {                                               \
    _Pragma("unroll")                                                        \
    for (int ks = 0; ks < 2; ++ks) {                                         \
      f16x8 af[4], bf[4];                                                    \
      _Pragma("unroll")                                                      \
      for (int mi = 0; mi < 4; ++mi)                                         \
        af[mi] = *(const f16x8*)(As_ + (wy*64 + mi*16 + l15) * 64 +          \
                                 (((ks*4 + quad) ^ sw) * 8));                \
      _Pragma("unroll")                                                      \
      for (int nt = 0; nt < 2; ++nt) {                                       \
        _Pragma("unroll")                                                    \
        for (int ni = 0; ni < 4; ++ni)                                       \
          bf[ni] = *(const f16x8*)(Bs_ + (nt*128 + wx*64 + ni*16 + l15) * 64 + \
                                   (((ks*4 + quad) ^ sw) * 8));              \
        _Pragma("unroll")                                                    \
        for (int mi = 0; mi < 4; ++mi)                                       \
          _Pragma("unroll")                                                  \
          for (int ni = 0; ni < 4; ++ni)                                     \
            acc[nt][mi][ni] = __builtin_amdgcn_mfma_f32_16x16x32_f16(        \
                af[mi], bf[ni], acc[nt][mi][ni], 0, 0, 0);                   \
      }                                                                      \
    } } while (0)

  // ---- counted-vmcnt pipeline over 4 kc slices (8 loads per STAGE/thread)
  STAGE(0, As0, Bs0);                        // out: 8
  STAGE(1, As1, Bs1);                        // out: 16
  asm volatile("s_waitcnt vmcnt(8)" ::: "memory");   // kc0 landed
  __builtin_amdgcn_sched_barrier(0);
  bar();
  COMPUTE(As0, Bs0);                         // kc0
  bar();                                     // b0 free (no drain!)
  STAGE(2, As0, Bs0);                        // out: kc1(8)+kc2(8)
  asm volatile("s_waitcnt vmcnt(8)" ::: "memory");   // kc1 landed
  __builtin_amdgcn_sched_barrier(0);
  bar();
  COMPUTE(As1, Bs1);                         // kc1
  bar();                                     // b1 free
  STAGE(3, As1, Bs1);                        // out: kc2(8)+kc3(8)
  asm volatile("s_waitcnt vmcnt(8)" ::: "memory");   // kc2 landed
  __builtin_amdgcn_sched_barrier(0);
  bar();
  COMPUTE(As0, Bs0);                         // kc2
  asm volatile("s_waitcnt vmcnt(0)" ::: "memory");   // kc3 landed
  __builtin_amdgcn_sched_barrier(0);
  bar();
  COMPUTE(As1, Bs1);                         // kc3
#undef STAGE
#undef COMPUTE

  // ---- epilogue (once per block): per-row top-2 over all 256 cols
  float scv[2][4];
  #pragma unroll
  for (int nt = 0; nt < 2; ++nt)
    #pragma unroll
    for (int ni = 0; ni < 4; ++ni)
      scv[nt][ni] = sc[n0 + nt * 128 + wx * 64 + ni * 16 + l15];

  float s1[16], s2[16]; int i1[16];
  #pragma unroll
  for (int mi = 0; mi < 4; ++mi)
    #pragma unroll
    for (int r = 0; r < 4; ++r) {
      const int q = mi * 4 + r;
      float a1 = INFINITY, a2 = INFINITY; int ai = 0x7fffffff;
      #pragma unroll
      for (int nt = 0; nt < 2; ++nt)
        #pragma unroll
        for (int ni = 0; ni < 4; ++ni) {       // (nt,ni) ascending -> k ascending
          const float sv = fmaf(-0.0078125f, acc[nt][mi][ni][r], scv[nt][ni]);  // -2/256
          const int   k  = n0 + nt * 128 + wx * 64 + ni * 16 + l15;
          if (sv < a1) { a2 = a1; a1 = sv; ai = k; }
          else if (sv < a2) a2 = sv;
        }
      s1[q] = a1; s2[q] = a2; i1[q] = ai;
    }

  #pragma unroll
  for (int off = 1; off <= 8; off <<= 1)
    #pragma unroll
    for (int q = 0; q < 16; ++q) {
      const float o1 = __shfl_xor(s1[q], off);
      const float o2 = __shfl_xor(s2[q], off);
      const int   oi = __shfl_xor(i1[q], off);
      const float n2 = fminf(fminf(s2[q], o2), fmaxf(s1[q], o1));
      if (o1 < s1[q] || (o1 == s1[q] && oi < i1[q])) { s1[q] = o1; i1[q] = oi; }
      s2[q] = n2;
    }

  __syncthreads();
  if (l15 == 0) {
    #pragma unroll
    for (int mi = 0; mi < 4; ++mi)
      #pragma unroll
      for (int r = 0; r < 4; ++r) {
        const int q  = mi * 4 + r;
        const int ml = wy * 64 + mi * 16 + quad * 4 + r;   // 0..255
        mr1[ml * 2 + wx] = s1[q];
        mr2[ml * 2 + wx] = s2[q];
        mri[ml * 2 + wx] = i1[q];
      }
  }
  __syncthreads();
  if (tid < 256) {
    float a1 = mr1[tid * 2], a2 = mr2[tid * 2]; int ai = mri[tid * 2];
    const float b1 = mr1[tid * 2 + 1], b2 = mr2[tid * 2 + 1];
    const int   bi = mri[tid * 2 + 1];
    if (b1 < a1 || (b1 == a1 && bi < ai)) { a2 = fminf(a1, b2); a1 = b1; ai = bi; }
    else a2 = fminf(a2, b1);
    const size_t o = (size_t)bx * Mm + (size_t)(m0 + tid);  // split = 256-col window
    pd1[o] = a1; pd2[o] = a2; pi1[o] = ai;
  }
}

// ---------------------------------------------------------------------------
// combine the NSPL partials per row; flag near-ties and emit candidate pairs.
// A code can only be the true argmin if its fast score <= a1 + MARGIN (same
// eps <= MARGIN/2 assumption as the gap test). Splits with s1 <= thr give
// their winner; splits with s2 <= thr (rare) need all 256 codes enumerated.
// ---------------------------------------------------------------------------
__global__ void k_combine(const float* __restrict__ pd1, const float* __restrict__ pd2,
                          const int* __restrict__ pi1, int* __restrict__ idxf,
                          int* __restrict__ rc, int* __restrict__ rlist,
                          int* __restrict__ pairs, int* __restrict__ slist,
                          float* __restrict__ outIdx) {
  const int m = blockIdx.x * blockDim.x + threadIdx.x;
  if (m >= Mm) return;
  float a1 = INFINITY, a2 = INFINITY; int ai = 0x7fffffff;
  for (int spl = 0; spl < NSPL; ++spl) {         // spl ascending -> k ascending
    const size_t o = (size_t)spl * Mm + m;
    const float b1 = pd1[o], b2 = pd2[o]; const int bi = pi1[o];
    if (b1 < a1 || (b1 == a1 && bi < ai)) { a2 = fminf(a1, b2); a1 = b1; ai = bi; }
    else a2 = fminf(a2, b1);
  }
  idxf[m]   = ai;
  outIdx[m] = (float)ai;
  if (a2 - a1 <= RESCAN_MARGIN) {
    const int p = atomicAdd(&rc[0], 1);
    if (p < ZG_CAP) {
      rlist[p] = m;
      const float thr = a1 + RESCAN_MARGIN;
      // pass 1: count candidates
      int nc = 0;
      for (int spl = 0; spl < NSPL; ++spl) {
        const size_t o = (size_t)spl * Mm + m;
        if (pd2[o] <= thr) nc += 256;
        else if (pd1[o] <= thr) ++nc;
      }
      const int base = atomicAdd(&rc[1], nc);
      if (base + nc <= PAIR_CAP) {
        int wp = base;
        for (int spl = 0; spl < NSPL; ++spl) {
          const size_t o = (size_t)spl * Mm + m;
          const float b1 = pd1[o], b2 = pd2[o];
          if (b2 <= thr) {
            const int k0 = spl * 256;
            for (int c = 0; c < 256; ++c) pairs[wp++] = (p << 13) | (k0 + c);
          } else if (b1 <= thr) {
            pairs[wp++] = (p << 13) | pi1[o];
          }
        }
      } else {
        // overflow: sentinel-fill our in-range slice (no holes), divert to slow
        for (int q = base; q < PAIR_CAP; ++q) pairs[q] = -1;
        const int s = atomicAdd(&rc[2], 1); slist[s] = m;
      }
    } else {
      // zg overflow: full slow scan for this row
      const int s = atomicAdd(&rc[2], 1); slist[s] = m;
    }
  }
}

// ---------------------------------------------------------------------------
// gather flagged rows into compact zg; np norms; init packed minima
// ---------------------------------------------------------------------------
__global__ void k_gather(const float* __restrict__ z, const int* __restrict__ rc,
                         const int* __restrict__ rlist, float* __restrict__ zg,
                         float* __restrict__ Ag, unsigned long long* __restrict__ pbrow) {
  __shared__ float zr[Dd];
  const int cnt = min(rc[0], ZG_CAP);
  for (int it = blockIdx.x; it < cnt; it += gridDim.x) {
    const int m = rlist[it];
    const int b = m / Tt, t = m & (Tt - 1);
    __syncthreads();
    zr[threadIdx.x] = z[(size_t)b * Dd * Tt + (size_t)threadIdx.x * Tt + t];
    __syncthreads();
    zg[(size_t)it * Dd + threadIdx.x] = zr[threadIdx.x];
    if (threadIdx.x == 0) { Ag[it] = np_sumsq256(zr); pbrow[it] = ~0ull; }
  }
}

// ---------------------------------------------------------------------------
// candidate-pair exact rescan: one thread per (row,code) pair; np-faithful
// fp64 dot (same segment grouping / rounding sequence as the full scan),
// packed (orderable f32, idx) atomicMin per row.
// ---------------------------------------------------------------------------
__global__ __launch_bounds__(256)
void k_rescan_pairs(const float* __restrict__ cb, const float* __restrict__ sc,
                    const int* __restrict__ rc, const float* __restrict__ zg,
                    const float* __restrict__ Ag,
                    const int* __restrict__ pairs,
                    unsigned long long* __restrict__ pbrow) {
  const int n = min(rc[1], PAIR_CAP);
  const int i = blockIdx.x * 256 + threadIdx.x;
  if (i >= n) return;
  const int pr = pairs[i];
  if (pr < 0) return;                            // overflow sentinel
  const int it = pr >> 13, k = pr & (Kk - 1);
  const float* __restrict__ zp = zg + (size_t)it * Dd;
  const float* __restrict__ cp = cb + (size_t)k * Dd;
  double M8 = 0.0;
  #pragma unroll
  for (int sg = 0; sg < 8; ++sg) {
    double a0 = 0.0, a1 = 0.0, a2 = 0.0, a3 = 0.0;
    #pragma unroll
    for (int j = 0; j < 32; j += 4) {
      const float4 c4 = *(const float4*)(cp + sg * 32 + j);
      const float4 z4 = *(const float4*)(zp + sg * 32 + j);
      a0 = fma((double)c4.x, (double)z4.x, a0);
      a1 = fma((double)c4.y, (double)z4.y, a1);
      a2 = fma((double)c4.z, (double)z4.z, a2);
      a3 = fma((double)c4.w, (double)z4.w, a3);
    }
    M8 += (a0 + a1) + (a2 + a3);
  }
  const float M  = (float)M8;
  const float t1 = __fsub_rn(Ag[it], __fmul_rn(2.0f, M));
  const float dq = __fadd_rn(t1, sc[k]);
  unsigned int fb = __float_as_uint(dq);
  fb = (fb & 0x80000000u) ? ~fb : (fb | 0x80000000u);
  const unsigned long long pack = ((unsigned long long)fb << 32) | (unsigned)k;
  atomicMin(pbrow + it, pack);
}

__global__ void k_rescan_final(const int* __restrict__ rc, const int* __restrict__ rlist,
                               const unsigned long long* __restrict__ pbrow,
                               int* __restrict__ idxf, float* __restrict__ outIdx) {
  const int cnt = min(rc[0], ZG_CAP);
  const int it = blockIdx.x * blockDim.x + threadIdx.x;
  if (it < cnt) {
    const unsigned long long pb = pbrow[it];
    if (pb != ~0ull) {                           // untouched => slow-path row
      const int idx = (int)(unsigned)(pb & 0xFFFFFFFFull);
      const int m = rlist[it];
      idxf[m] = idx; outIdx[m] = (float)idx;
    }
  }
}

// overflow fallback: normally 0 iterations
__global__ void k_rescan_slow(const float* __restrict__ z, const float* __restrict__ cb,
                              const float* __restrict__ sc,
                              const int* __restrict__ rc, const int* __restrict__ slist,
                              int* __restrict__ idxf, float* __restrict__ outIdx) {
  __shared__ float zrow[Dd];
  __shared__ float Ash;
  __shared__ float sval[256];
  __shared__ int   sidx[256];
  const int tid = threadIdx.x;
  const int cnt = rc[2];
  for (int it = blockIdx.x; it < cnt; it += gridDim.x) {
    const int m = slist[it];
    const int b = m / Tt, t = m & (Tt - 1);
    __syncthreads();
    zrow[tid] = z[(size_t)b * Dd * Tt + (size_t)tid * Tt + t];
    __syncthreads();
    if (tid == 0) Ash = np_sumsq256(zrow);
    __syncthreads();
    const float A = Ash;
    float best = INFINITY; int bi = 0x7fffffff;
    for (int k = tid; k < Kk; k += 256) {
      const float* cr = cb + (size_t)k * Dd;
      double a0 = 0.0, a1 = 0.0, a2 = 0.0, a3 = 0.0;
      for (int d = 0; d < Dd; d += 4) {
        const float4 c4 = *(const float4*)(cr + d);
        a0 = fma((double)c4.x, (double)zrow[d+0], a0);
        a1 = fma((double)c4.y, (double)zrow[d+1], a1);
        a2 = fma((double)c4.z, (double)zrow[d+2], a2);
        a3 = fma((double)c4.w, (double)zrow[d+3], a3);
      }
      const float M  = (float)((a0 + a1) + (a2 + a3));
      const float t1 = __fsub_rn(A, __fmul_rn(2.0f, M));
      const float dq = __fadd_rn(t1, sc[k]);
      if (dq < best) { best = dq; bi = k; }
    }
    sval[tid] = best; sidx[tid] = bi;
    __syncthreads();
    for (int off = 128; off; off >>= 1) {
      if (tid < off) {
        if (sval[tid+off] < sval[tid] ||
            (sval[tid+off] == sval[tid] && sidx[tid+off] < sidx[tid])) {
          sval[tid] = sval[tid+off]; sidx[tid] = sidx[tid+off];
        }
      }
      __syncthreads();
    }
    if (tid == 0) { idxf[m] = sidx[0]; outIdx[m] = (float)sidx[0]; }
    __syncthreads();
  }
}

// ---------------------------------------------------------------------------
// fused gather + transpose + STE + loss: out[b][d][t] = z + (cb[idx] - z)
// ---------------------------------------------------------------------------
__global__ void k_out(const float* __restrict__ z, const float* __restrict__ cb,
                      const int* __restrict__ idxf,
                      float* __restrict__ outZ, double* __restrict__ loss_accum) {
  __shared__ float tile[64][65];          // [d][t]
  const int tid = threadIdx.x;
  const int bidx = blockIdx.x;            // 8 * 4 * 32 = 1024
  const int b  = bidx >> 7;
  const int dt = (bidx >> 5) & 3;
  const int tt = bidx & 31;
  const int d0 = dt * 64, t0 = tt * 64;
  {
    const int r = tid >> 2, seg = tid & 3;
    const int idx = idxf[b * Tt + t0 + r];
    const float* src = cb + (size_t)idx * Dd + d0 + seg * 16;
    #pragma unroll
    for (int q4 = 0; q4 < 4; ++q4) {
      const float4 v = *(const float4*)(src + q4 * 4);
      tile[seg * 16 + q4 * 4 + 0][r] = v.x;
      tile[seg * 16 + q4 * 4 + 1][r] = v.y;
      tile[seg * 16 + q4 * 4 + 2][r] = v.z;
      tile[seg * 16 + q4 * 4 + 3][r] = v.w;
    }
  }
  __syncthreads();
  const float* zbase = z + ((size_t)b * Dd + d0) * Tt + t0;
  float*       obase = outZ + ((size_t)b * Dd + d0) * Tt + t0;
  double ls = 0.0;
  #pragma unroll
  for (int p = 0; p < 4; ++p) {
    const int d  = p * 16 + (tid >> 4);
    const int t4 = (tid & 15) * 4;
    const float4 zv = *(const float4*)(zbase + (size_t)d * Tt + t4);
    const float q0 = tile[d][t4+0], q1 = tile[d][t4+1];
    const float q2 = tile[d][t4+2], q3 = tile[d][t4+3];
    const float r0 = q0 - zv.x, r1 = q1 - zv.y, r2 = q2 - zv.z, r3 = q3 - zv.w;
    float4 o;
    o.x = zv.x + r0; o.y = zv.y + r1; o.z = zv.z + r2; o.w = zv.w + r3;
    *(float4*)(obase + (size_t)d * Tt + t4) = o;
    ls += (double)r0*r0 + (double)r1*r1 + (double)r2*r2 + (double)r3*r3;
  }
  #pragma unroll
  for (int off = 32; off; off >>= 1) ls += __shfl_down(ls, off);
  if ((tid & 63) == 0) atomicAdd(loss_accum, ls);
}

__global__ void k_finalize(const double* __restrict__ loss_accum, float* __restrict__ outLoss) {
  const double mean = *loss_accum / (double)((size_t)Bz * Dd * Tt);
  *outLoss = (float)(mean + 0.1 * mean);
}

// ---------------------------------------------------------------------------
extern "C" void kernel_launch(void* const* d_in, const int* in_sizes, int n_in,
                              void* d_out, int out_size, void* d_ws, size_t ws_size,
                              hipStream_t stream) {
  (void)in_sizes; (void)n_in; (void)out_size; (void)ws_size;
  const float* z  = (const float*)d_in[0];   // (B, D, T) fp32
  const float* cb = (const float*)d_in[1];   // (K, D)    fp32

  float* outZ    = (float*)d_out;
  float* outIdx  = outZ + (size_t)Bz * Dd * Tt;
  float* outLoss = outIdx + Mm;

  char* w = (char*)d_ws;
  double*    loss_accum = (double*)w;    w += 16;
  int*       rc         = (int*)w;       w += 16;   // [0]=rows [1]=pairs [2]=slow
  int*       rlist      = (int*)w;       w += sizeof(int)   * Mm;
  int*       slist      = (int*)w;       w += sizeof(int)   * Mm;
  int*       idxf       = (int*)w;       w += sizeof(int)   * Mm;
  float*     sc         = (float*)w;     w += sizeof(float) * Kk;
  _Float16*  Ah         = (_Float16*)w;  w += sizeof(_Float16) * (size_t)Mm * Dd;
  _Float16*  Bh         = (_Float16*)w;  w += sizeof(_Float16) * (size_t)Kk * Dd;
  float*     zg         = (float*)w;     w += sizeof(float) * (size_t)ZG_CAP * Dd;
  float*     Ag         = (float*)w;     w += sizeof(float) * ZG_CAP;
  unsigned long long* pbrow = (unsigned long long*)w; w += sizeof(unsigned long long) * ZG_CAP;
  int*       pairs      = (int*)w;       w += sizeof(int) * PAIR_CAP;
  float*     pd1        = (float*)w;     w += sizeof(float) * (size_t)NSPL * Mm;
  float*     pd2        = (float*)w;     w += sizeof(float) * (size_t)NSPL * Mm;
  int*       pi1        = (int*)w;       /* total ~25 MB */

  k_pre         <<<dim3(2304), 256, 0, stream>>>(z, cb, Ah, Bh, sc, loss_accum, rc);
  k_mfma        <<<dim3((Mm / 256) * (Kk / 256)), 512, 0, stream>>>(Ah, Bh, sc, pd1, pd2, pi1);
  k_combine     <<<dim3(Mm / 256), 256, 0, stream>>>(pd1, pd2, pi1, idxf, rc, rlist, pairs, slist, outIdx);
  k_gather      <<<dim3(256), 256, 0, stream>>>(z, rc, rlist, zg, Ag, pbrow);
  k_rescan_pairs<<<dim3(PAIR_CAP / 256), 256, 0, stream>>>(cb, sc, rc, zg, Ag, pairs, pbrow);
  k_rescan_slow <<<dim3(64), 256, 0, stream>>>(z, cb, sc, rc, slist, idxf, outIdx);
  k_rescan_final<<<dim3(ZG_CAP / 256), 256, 0, stream>>>(rc, rlist, pbrow, idxf, outIdx);
  k_out         <<<dim3(1024), 256, 0, stream>>>(z, cb, idxf, outZ, loss_accum);
  k_finalize    <<<dim3(1), 1, 0, stream>>>(loss_accum, outLoss);
}

// Round 6
// 368.298 us; speedup vs baseline: 1.2327x; 1.0109x over previous
//
#include <hip/hip_runtime.h>
#include <hip/hip_bf16.h>
#include <float.h>
#include <math.h>

#define Bz 8
#define Dd 256
#define Tt 2048
#define Kk 8192
#define Mm (Bz*Tt)          // 16384 rows (b*T + t)

// Scorer v14: v10's proven core (2-barrier kc loop, gld16 staging, XOR granule
// swizzle, natural dispatch order) at a SMALLER block: 128 rows x 128 cols,
// 4 waves (2wy x 2wx, 64x64 wave-tiles), LDS 35 KB, acc[4][4] (64 VGPR),
// __launch_bounds__(256,4) -> 4 blocks/CU = 16 waves/CU. Mechanism: v9-v13
// were all stuck at MfmaUtil ~15% with 2-3 waves/SIMD; per-wave MFMA issue
// gaps need TLP to fill (Guideline 1), not more schedule surgery.
// Splits = 128 cols -> NSPL 64.
#define NSPL 64

#define ZG_CAP 4096
#define PAIR_CAP 131072     // candidate (row,code) pairs; expected ~6K

// Margin: covers f16 fast-pass score error + np fp32 quantization straddle
#define RESCAN_MARGIN 6e-4f

typedef __attribute__((ext_vector_type(8))) _Float16 f16x8;
typedef __attribute__((ext_vector_type(4))) float    f32x4;

// async global->LDS DMA, 16 B per lane; lds dest = wave-uniform base + lane*16
__device__ __forceinline__ void gld16(const void* g, void* l) {
  __builtin_amdgcn_global_load_lds(
      (const __attribute__((address_space(1))) void*)g,
      (__attribute__((address_space(3))) void*)l, 16, 0, 0);
}

// ---------------------------------------------------------------------------
// numpy-faithful pairwise sum of squares (blocksize-128 pairwise, 8 accums)
// ---------------------------------------------------------------------------
__device__ __forceinline__ float np_sumsq128(const float* __restrict__ x) {
  float r0 = __fmul_rn(x[0], x[0]);
  float r1 = __fmul_rn(x[1], x[1]);
  float r2 = __fmul_rn(x[2], x[2]);
  float r3 = __fmul_rn(x[3], x[3]);
  float r4 = __fmul_rn(x[4], x[4]);
  float r5 = __fmul_rn(x[5], x[5]);
  float r6 = __fmul_rn(x[6], x[6]);
  float r7 = __fmul_rn(x[7], x[7]);
  for (int i = 8; i < 128; i += 8) {
    r0 = __fadd_rn(r0, __fmul_rn(x[i+0], x[i+0]));
    r1 = __fadd_rn(r1, __fmul_rn(x[i+1], x[i+1]));
    r2 = __fadd_rn(r2, __fmul_rn(x[i+2], x[i+2]));
    r3 = __fadd_rn(r3, __fmul_rn(x[i+3], x[i+3]));
    r4 = __fadd_rn(r4, __fmul_rn(x[i+4], x[i+4]));
    r5 = __fadd_rn(r5, __fmul_rn(x[i+5], x[i+5]));
    r6 = __fadd_rn(r6, __fmul_rn(x[i+6], x[i+6]));
    r7 = __fadd_rn(r7, __fmul_rn(x[i+7], x[i+7]));
  }
  return __fadd_rn(__fadd_rn(__fadd_rn(r0, r1), __fadd_rn(r2, r3)),
                   __fadd_rn(__fadd_rn(r4, r5), __fadd_rn(r6, r7)));
}
__device__ __forceinline__ float np_sumsq256(const float* __restrict__ x) {
  return __fadd_rn(np_sumsq128(x), np_sumsq128(x + 128));
}

// ---------------------------------------------------------------------------
// k_pre: fused [cast_z | cast_cb | prep] by blockIdx range (fewer launches)
// ---------------------------------------------------------------------------
__global__ void k_pre(const float* __restrict__ z, const float* __restrict__ cb,
                      _Float16* __restrict__ Ah, _Float16* __restrict__ Bh,
                      float* __restrict__ sc,
                      double* __restrict__ loss_accum, int* __restrict__ rc) {
  const int bid = blockIdx.x;
  const int tid = threadIdx.x;
  if (bid < 1024) {
    // ---- transpose-cast z (B,D,T) f32 -> Ah (M,D) f16
    __shared__ _Float16 tile[64][64 + 8];
    const int b  = bid >> 7;
    const int dt = (bid >> 5) & 3;
    const int tt = bid & 31;
    const int d0 = dt * 64, t0 = tt * 64;
    const float* zb = z + ((size_t)b * Dd + d0) * Tt + t0;
    #pragma unroll
    for (int p = 0; p < 4; ++p) {
      const int d  = p * 16 + (tid >> 4);
      const int tl = (tid & 15) * 4;
      const float4 v = *(const float4*)(zb + (size_t)d * Tt + tl);
      tile[tl+0][d] = (_Float16)v.x;
      tile[tl+1][d] = (_Float16)v.y;
      tile[tl+2][d] = (_Float16)v.z;
      tile[tl+3][d] = (_Float16)v.w;
    }
    __syncthreads();
    const int r = tid >> 2, seg = tid & 3;
    const int m = b * Tt + t0 + r;
    int4* dst = (int4*)(Ah + (size_t)m * Dd + d0 + seg * 16);
    const int4* srcv = (const int4*)(&tile[r][seg * 16]);
    dst[0] = srcv[0];
    dst[1] = srcv[1];
  } else if (bid < 2048) {
    // ---- cast codebook f32 -> f16, prescaled by 256
    const size_t g = (size_t)(bid - 1024) * 256 + tid;
    const float4 v0 = *(const float4*)(cb + g * 8);
    const float4 v1 = *(const float4*)(cb + g * 8 + 4);
    f16x8 o;
    o[0] = (_Float16)(v0.x * 256.f); o[1] = (_Float16)(v0.y * 256.f);
    o[2] = (_Float16)(v0.z * 256.f); o[3] = (_Float16)(v0.w * 256.f);
    o[4] = (_Float16)(v1.x * 256.f); o[5] = (_Float16)(v1.y * 256.f);
    o[6] = (_Float16)(v1.z * 256.f); o[7] = (_Float16)(v1.w * 256.f);
    *(f16x8*)(Bh + g * 8) = o;
  } else {
    // ---- np-faithful codebook norms (8 lanes own np's 8 acc chains)
    if (bid == 2048 && tid == 0) {
      *loss_accum = 0.0; rc[0] = 0; rc[1] = 0; rc[2] = 0;
    }
    const int gid = (bid - 2048) * 256 + tid;
    const int lane = gid & 63;
    const int j = lane & 7, sub = lane >> 3;
    const int row = (gid >> 6) * 8 + sub;
    if (row >= Kk) return;
    const float* x = cb + (size_t)row * Dd;
    float c0 = __fmul_rn(x[j], x[j]);
    float c1 = __fmul_rn(x[128 + j], x[128 + j]);
    #pragma unroll
    for (int i = 8; i < 128; i += 8) {
      c0 = __fadd_rn(c0, __fmul_rn(x[j + i], x[j + i]));
      c1 = __fadd_rn(c1, __fmul_rn(x[128 + j + i], x[128 + j + i]));
    }
    #pragma unroll
    for (int off = 1; off <= 4; off <<= 1) {
      c0 = __fadd_rn(c0, __shfl_xor(c0, off));
      c1 = __fadd_rn(c1, __shfl_xor(c1, off));
    }
    if (j == 0) sc[row] = __fadd_rn(c0, c1);
  }
}

// ---------------------------------------------------------------------------
// f16 MFMA score pass v14 (128x128 block, 4 waves, 4 blocks/CU)
// ---------------------------------------------------------------------------
__global__ __launch_bounds__(256, 4)
void k_mfma(const _Float16* __restrict__ Ah, const _Float16* __restrict__ Bh,
            const float* __restrict__ sc,
            float* __restrict__ pd1, float* __restrict__ pd2, int* __restrict__ pi1) {
  __shared__ __align__(16) _Float16 As[128 * 64];   // 16 KB, dense 128 B rows
  __shared__ __align__(16) _Float16 Bs[128 * 64];   // 16 KB
  __shared__ float mr1[256];
  __shared__ float mr2[256];
  __shared__ int   mri[256];

  const int tid  = threadIdx.x;
  const int bx   = blockIdx.x & 63;      // 64 n-tiles of 128 cols (natural order)
  const int by   = blockIdx.x >> 6;      // 128 m-tiles of 128 rows
  const int m0   = by * 128, n0 = bx * 128;
  const int w    = tid >> 6, lane = tid & 63;
  const int wy   = w >> 1, wx = w & 1;   // 2 row-bands x 2 col-halves
  const int l15  = lane & 15, quad = lane >> 4;
  const int lhi  = lane >> 3, llo = lane & 7;   // staging roles
  const int p    = llo ^ lhi;                   // swizzled source granule
  const int sw   = l15 & 7;                     // read-side swizzle key

  f32x4 acc[4][4];
  #pragma unroll
  for (int mi = 0; mi < 4; ++mi)
    #pragma unroll
    for (int ni = 0; ni < 4; ++ni)
      acc[mi][ni] = (f32x4){0.f, 0.f, 0.f, 0.f};

  // ---- K loop: per kc stage A (128x64) + B (128x64), then 2 ks x 16 MFMA
  for (int kc = 0; kc < 4; ++kc) {
    __syncthreads();                           // prior LDS reads done
    #pragma unroll
    for (int c4 = 0; c4 < 4; ++c4) {
      const int c  = w * 4 + c4;               // chunk: 8 rows x 128 B
      const int r8 = c * 8 + lhi;
      gld16(Ah + (size_t)(m0 + r8) * Dd + kc * 64 + p * 8, As + c * 512);
      gld16(Bh + (size_t)(n0 + r8) * Dd + kc * 64 + p * 8, Bs + c * 512);
    }
    __syncthreads();                           // drains vmcnt -> data visible
    #pragma unroll
    for (int ks = 0; ks < 2; ++ks) {
      f16x8 af[4], bf[4];
      #pragma unroll
      for (int mi = 0; mi < 4; ++mi)
        af[mi] = *(const f16x8*)(As + (wy*64 + mi*16 + l15) * 64 + (((ks*4 + quad) ^ sw) * 8));
      #pragma unroll
      for (int ni = 0; ni < 4; ++ni)
        bf[ni] = *(const f16x8*)(Bs + (wx*64 + ni*16 + l15) * 64 + (((ks*4 + quad) ^ sw) * 8));
      #pragma unroll
      for (int mi = 0; mi < 4; ++mi)
        #pragma unroll
        for (int ni = 0; ni < 4; ++ni)
          acc[mi][ni] = __builtin_amdgcn_mfma_f32_16x16x32_f16(af[mi], bf[ni], acc[mi][ni], 0, 0, 0);
    }
  }

  // ---- epilogue: per-row top-2 over this block's 128 cols
  float scv[4];
  #pragma unroll
  for (int ni = 0; ni < 4; ++ni)
    scv[ni] = sc[n0 + wx * 64 + ni * 16 + l15];

  float s1[16], s2[16]; int i1[16];
  #pragma unroll
  for (int mi = 0; mi < 4; ++mi)
    #pragma unroll
    for (int r = 0; r < 4; ++r) {
      const int q = mi * 4 + r;
      float a1 = INFINITY, a2 = INFINITY; int ai = 0x7fffffff;
      #pragma unroll
      for (int ni = 0; ni < 4; ++ni) {         // ni ascending -> k ascending
        const float sv = fmaf(-0.0078125f, acc[mi][ni][r], scv[ni]);  // -2/256
        const int   k  = n0 + wx * 64 + ni * 16 + l15;
        if (sv < a1) { a2 = a1; a1 = sv; ai = k; }
        else if (sv < a2) a2 = sv;
      }
      s1[q] = a1; s2[q] = a2; i1[q] = ai;
    }

  #pragma unroll
  for (int off = 1; off <= 8; off <<= 1)
    #pragma unroll
    for (int q = 0; q < 16; ++q) {
      const float o1 = __shfl_xor(s1[q], off);
      const float o2 = __shfl_xor(s2[q], off);
      const int   oi = __shfl_xor(i1[q], off);
      const float n2 = fminf(fminf(s2[q], o2), fmaxf(s1[q], o1));
      if (o1 < s1[q] || (o1 == s1[q] && oi < i1[q])) { s1[q] = o1; i1[q] = oi; }
      s2[q] = n2;
    }

  __syncthreads();                             // As/Bs reads done; mr reuse ok
  if (l15 == 0) {
    #pragma unroll
    for (int mi = 0; mi < 4; ++mi)
      #pragma unroll
      for (int r = 0; r < 4; ++r) {
        const int q  = mi * 4 + r;
        const int ml = wy * 64 + mi * 16 + quad * 4 + r;   // 0..127
        mr1[ml * 2 + wx] = s1[q];
        mr2[ml * 2 + wx] = s2[q];
        mri[ml * 2 + wx] = i1[q];
      }
  }
  __syncthreads();
  if (tid < 128) {
    float a1 = mr1[tid * 2], a2 = mr2[tid * 2]; int ai = mri[tid * 2];
    const float b1 = mr1[tid * 2 + 1], b2 = mr2[tid * 2 + 1];
    const int   bi = mri[tid * 2 + 1];
    if (b1 < a1 || (b1 == a1 && bi < ai)) { a2 = fminf(a1, b2); a1 = b1; ai = bi; }
    else a2 = fminf(a2, b1);
    const size_t o = (size_t)bx * Mm + (size_t)(m0 + tid);  // split = 128-col window
    pd1[o] = a1; pd2[o] = a2; pi1[o] = ai;
  }
}

// ---------------------------------------------------------------------------
// combine the NSPL partials per row; flag near-ties and emit candidate pairs.
// A code can only be the true argmin if its fast score <= a1 + MARGIN (same
// eps <= MARGIN/2 assumption as the gap test). Splits with s1 <= thr give
// their winner; splits with s2 <= thr (rare) need all 128 codes enumerated.
// ---------------------------------------------------------------------------
__global__ void k_combine(const float* __restrict__ pd1, const float* __restrict__ pd2,
                          const int* __restrict__ pi1, int* __restrict__ idxf,
                          int* __restrict__ rc, int* __restrict__ rlist,
                          int* __restrict__ pairs, int* __restrict__ slist,
                          float* __restrict__ outIdx) {
  const int m = blockIdx.x * blockDim.x + threadIdx.x;
  if (m >= Mm) return;
  float a1 = INFINITY, a2 = INFINITY; int ai = 0x7fffffff;
  for (int spl = 0; spl < NSPL; ++spl) {         // spl ascending -> k ascending
    const size_t o = (size_t)spl * Mm + m;
    const float b1 = pd1[o], b2 = pd2[o]; const int bi = pi1[o];
    if (b1 < a1 || (b1 == a1 && bi < ai)) { a2 = fminf(a1, b2); a1 = b1; ai = bi; }
    else a2 = fminf(a2, b1);
  }
  idxf[m]   = ai;
  outIdx[m] = (float)ai;
  if (a2 - a1 <= RESCAN_MARGIN) {
    const int p = atomicAdd(&rc[0], 1);
    if (p < ZG_CAP) {
      rlist[p] = m;
      const float thr = a1 + RESCAN_MARGIN;
      // pass 1: count candidates
      int nc = 0;
      for (int spl = 0; spl < NSPL; ++spl) {
        const size_t o = (size_t)spl * Mm + m;
        if (pd2[o] <= thr) nc += 128;
        else if (pd1[o] <= thr) ++nc;
      }
      const int base = atomicAdd(&rc[1], nc);
      if (base + nc <= PAIR_CAP) {
        int wp = base;
        for (int spl = 0; spl < NSPL; ++spl) {
          const size_t o = (size_t)spl * Mm + m;
          const float b1 = pd1[o], b2 = pd2[o];
          if (b2 <= thr) {
            const int k0 = spl * 128;
            for (int c = 0; c < 128; ++c) pairs[wp++] = (p << 13) | (k0 + c);
          } else if (b1 <= thr) {
            pairs[wp++] = (p << 13) | pi1[o];
          }
        }
      } else {
        // overflow: sentinel-fill our in-range slice (no holes), divert to slow
        for (int q = base; q < PAIR_CAP; ++q) pairs[q] = -1;
        const int s = atomicAdd(&rc[2], 1); slist[s] = m;
      }
    } else {
      // zg overflow: full slow scan for this row
      const int s = atomicAdd(&rc[2], 1); slist[s] = m;
    }
  }
}

// ---------------------------------------------------------------------------
// gather flagged rows into compact zg; np norms; init packed minima
// ---------------------------------------------------------------------------
__global__ void k_gather(const float* __restrict__ z, const int* __restrict__ rc,
                         const int* __restrict__ rlist, float* __restrict__ zg,
                         float* __restrict__ Ag, unsigned long long* __restrict__ pbrow) {
  __shared__ float zr[Dd];
  const int cnt = min(rc[0], ZG_CAP);
  for (int it = blockIdx.x; it < cnt; it += gridDim.x) {
    const int m = rlist[it];
    const int b = m / Tt, t = m & (Tt - 1);
    __syncthreads();
    zr[threadIdx.x] = z[(size_t)b * Dd * Tt + (size_t)threadIdx.x * Tt + t];
    __syncthreads();
    zg[(size_t)it * Dd + threadIdx.x] = zr[threadIdx.x];
    if (threadIdx.x == 0) { Ag[it] = np_sumsq256(zr); pbrow[it] = ~0ull; }
  }
}

// ---------------------------------------------------------------------------
// candidate-pair exact rescan: one thread per (row,code) pair; np-faithful
// fp64 dot (same segment grouping / rounding sequence as the full scan),
// packed (orderable f32, idx) atomicMin per row.
// ---------------------------------------------------------------------------
__global__ __launch_bounds__(256)
void k_rescan_pairs(const float* __restrict__ cb, const float* __restrict__ sc,
                    const int* __restrict__ rc, const float* __restrict__ zg,
                    const float* __restrict__ Ag,
                    const int* __restrict__ pairs,
                    unsigned long long* __restrict__ pbrow) {
  const int n = min(rc[1], PAIR_CAP);
  const int i = blockIdx.x * 256 + threadIdx.x;
  if (i >= n) return;
  const int pr = pairs[i];
  if (pr < 0) return;                            // overflow sentinel
  const int it = pr >> 13, k = pr & (Kk - 1);
  const float* __restrict__ zp = zg + (size_t)it * Dd;
  const float* __restrict__ cp = cb + (size_t)k * Dd;
  double M8 = 0.0;
  #pragma unroll
  for (int sg = 0; sg < 8; ++sg) {
    double a0 = 0.0, a1 = 0.0, a2 = 0.0, a3 = 0.0;
    #pragma unroll
    for (int j = 0; j < 32; j += 4) {
      const float4 c4 = *(const float4*)(cp + sg * 32 + j);
      const float4 z4 = *(const float4*)(zp + sg * 32 + j);
      a0 = fma((double)c4.x, (double)z4.x, a0);
      a1 = fma((double)c4.y, (double)z4.y, a1);
      a2 = fma((double)c4.z, (double)z4.z, a2);
      a3 = fma((double)c4.w, (double)z4.w, a3);
    }
    M8 += (a0 + a1) + (a2 + a3);
  }
  const float M  = (float)M8;
  const float t1 = __fsub_rn(Ag[it], __fmul_rn(2.0f, M));
  const float dq = __fadd_rn(t1, sc[k]);
  unsigned int fb = __float_as_uint(dq);
  fb = (fb & 0x80000000u) ? ~fb : (fb | 0x80000000u);
  const unsigned long long pack = ((unsigned long long)fb << 32) | (unsigned)k;
  atomicMin(pbrow + it, pack);
}

__global__ void k_rescan_final(const int* __restrict__ rc, const int* __restrict__ rlist,
                               const unsigned long long* __restrict__ pbrow,
                               int* __restrict__ idxf, float* __restrict__ outIdx) {
  const int cnt = min(rc[0], ZG_CAP);
  const int it = blockIdx.x * blockDim.x + threadIdx.x;
  if (it < cnt) {
    const unsigned long long pb = pbrow[it];
    if (pb != ~0ull) {                           // untouched => slow-path row
      const int idx = (int)(unsigned)(pb & 0xFFFFFFFFull);
      const int m = rlist[it];
      idxf[m] = idx; outIdx[m] = (float)idx;
    }
  }
}

// overflow fallback: normally 0 iterations
__global__ void k_rescan_slow(const float* __restrict__ z, const float* __restrict__ cb,
                              const float* __restrict__ sc,
                              const int* __restrict__ rc, const int* __restrict__ slist,
                              int* __restrict__ idxf, float* __restrict__ outIdx) {
  __shared__ float zrow[Dd];
  __shared__ float Ash;
  __shared__ float sval[256];
  __shared__ int   sidx[256];
  const int tid = threadIdx.x;
  const int cnt = rc[2];
  for (int it = blockIdx.x; it < cnt; it += gridDim.x) {
    const int m = slist[it];
    const int b = m / Tt, t = m & (Tt - 1);
    __syncthreads();
    zrow[tid] = z[(size_t)b * Dd * Tt + (size_t)tid * Tt + t];
    __syncthreads();
    if (tid == 0) Ash = np_sumsq256(zrow);
    __syncthreads();
    const float A = Ash;
    float best = INFINITY; int bi = 0x7fffffff;
    for (int k = tid; k < Kk; k += 256) {
      const float* cr = cb + (size_t)k * Dd;
      double a0 = 0.0, a1 = 0.0, a2 = 0.0, a3 = 0.0;
      for (int d = 0; d < Dd; d += 4) {
        const float4 c4 = *(const float4*)(cr + d);
        a0 = fma((double)c4.x, (double)zrow[d+0], a0);
        a1 = fma((double)c4.y, (double)zrow[d+1], a1);
        a2 = fma((double)c4.z, (double)zrow[d+2], a2);
        a3 = fma((double)c4.w, (double)zrow[d+3], a3);
      }
      const float M  = (float)((a0 + a1) + (a2 + a3));
      const float t1 = __fsub_rn(A, __fmul_rn(2.0f, M));
      const float dq = __fadd_rn(t1, sc[k]);
      if (dq < best) { best = dq; bi = k; }
    }
    sval[tid] = best; sidx[tid] = bi;
    __syncthreads();
    for (int off = 128; off; off >>= 1) {
      if (tid < off) {
        if (sval[tid+off] < sval[tid] ||
            (sval[tid+off] == sval[tid] && sidx[tid+off] < sidx[tid])) {
          sval[tid] = sval[tid+off]; sidx[tid] = sidx[tid+off];
        }
      }
      __syncthreads();
    }
    if (tid == 0) { idxf[m] = sidx[0]; outIdx[m] = (float)sidx[0]; }
    __syncthreads();
  }
}

// ---------------------------------------------------------------------------
// fused gather + transpose + STE + loss: out[b][d][t] = z + (cb[idx] - z)
// ---------------------------------------------------------------------------
__global__ void k_out(const float* __restrict__ z, const float* __restrict__ cb,
                      const int* __restrict__ idxf,
                      float* __restrict__ outZ, double* __restrict__ loss_accum) {
  __shared__ float tile[64][65];          // [d][t]
  const int tid = threadIdx.x;
  const int bidx = blockIdx.x;            // 8 * 4 * 32 = 1024
  const int b  = bidx >> 7;
  const int dt = (bidx >> 5) & 3;
  const int tt = bidx & 31;
  const int d0 = dt * 64, t0 = tt * 64;
  {
    const int r = tid >> 2, seg = tid & 3;
    const int idx = idxf[b * Tt + t0 + r];
    const float* src = cb + (size_t)idx * Dd + d0 + seg * 16;
    #pragma unroll
    for (int q4 = 0; q4 < 4; ++q4) {
      const float4 v = *(const float4*)(src + q4 * 4);
      tile[seg * 16 + q4 * 4 + 0][r] = v.x;
      tile[seg * 16 + q4 * 4 + 1][r] = v.y;
      tile[seg * 16 + q4 * 4 + 2][r] = v.z;
      tile[seg * 16 + q4 * 4 + 3][r] = v.w;
    }
  }
  __syncthreads();
  const float* zbase = z + ((size_t)b * Dd + d0) * Tt + t0;
  float*       obase = outZ + ((size_t)b * Dd + d0) * Tt + t0;
  double ls = 0.0;
  #pragma unroll
  for (int p = 0; p < 4; ++p) {
    const int d  = p * 16 + (tid >> 4);
    const int t4 = (tid & 15) * 4;
    const float4 zv = *(const float4*)(zbase + (size_t)d * Tt + t4);
    const float q0 = tile[d][t4+0], q1 = tile[d][t4+1];
    const float q2 = tile[d][t4+2], q3 = tile[d][t4+3];
    const float r0 = q0 - zv.x, r1 = q1 - zv.y, r2 = q2 - zv.z, r3 = q3 - zv.w;
    float4 o;
    o.x = zv.x + r0; o.y = zv.y + r1; o.z = zv.z + r2; o.w = zv.w + r3;
    *(float4*)(obase + (size_t)d * Tt + t4) = o;
    ls += (double)r0*r0 + (double)r1*r1 + (double)r2*r2 + (double)r3*r3;
  }
  #pragma unroll
  for (int off = 32; off; off >>= 1) ls += __shfl_down(ls, off);
  if ((tid & 63) == 0) atomicAdd(loss_accum, ls);
}

__global__ void k_finalize(const double* __restrict__ loss_accum, float* __restrict__ outLoss) {
  const double mean = *loss_accum / (double)((size_t)Bz * Dd * Tt);
  *outLoss = (float)(mean + 0.1 * mean);
}

// ---------------------------------------------------------------------------
extern "C" void kernel_launch(void* const* d_in, const int* in_sizes, int n_in,
                              void* d_out, int out_size, void* d_ws, size_t ws_size,
                              hipStream_t stream) {
  (void)in_sizes; (void)n_in; (void)out_size; (void)ws_size;
  const float* z  = (const float*)d_in[0];   // (B, D, T) fp32
  const float* cb = (const float*)d_in[1];   // (K, D)    fp32

  float* outZ    = (float*)d_out;
  float* outIdx  = outZ + (size_t)Bz * Dd * Tt;
  float* outLoss = outIdx + Mm;

  char* w = (char*)d_ws;
  double*    loss_accum = (double*)w;    w += 16;
  int*       rc         = (int*)w;       w += 16;   // [0]=rows [1]=pairs [2]=slow
  int*       rlist      = (int*)w;       w += sizeof(int)   * Mm;
  int*       slist      = (int*)w;       w += sizeof(int)   * Mm;
  int*       idxf       = (int*)w;       w += sizeof(int)   * Mm;
  float*     sc         = (float*)w;     w += sizeof(float) * Kk;
  _Float16*  Ah         = (_Float16*)w;  w += sizeof(_Float16) * (size_t)Mm * Dd;
  _Float16*  Bh         = (_Float16*)w;  w += sizeof(_Float16) * (size_t)Kk * Dd;
  float*     zg         = (float*)w;     w += sizeof(float) * (size_t)ZG_CAP * Dd;
  float*     Ag         = (float*)w;     w += sizeof(float) * ZG_CAP;
  unsigned long long* pbrow = (unsigned long long*)w; w += sizeof(unsigned long long) * ZG_CAP;
  int*       pairs      = (int*)w;       w += sizeof(int) * PAIR_CAP;
  float*     pd1        = (float*)w;     w += sizeof(float) * (size_t)NSPL * Mm;
  float*     pd2        = (float*)w;     w += sizeof(float) * (size_t)NSPL * Mm;
  int*       pi1        = (int*)w;       /* total ~30 MB */

  k_pre         <<<dim3(2304), 256, 0, stream>>>(z, cb, Ah, Bh, sc, loss_accum, rc);
  k_mfma        <<<dim3((Mm / 128) * (Kk / 128)), 256, 0, stream>>>(Ah, Bh, sc, pd1, pd2, pi1);
  k_combine     <<<dim3(Mm / 256), 256, 0, stream>>>(pd1, pd2, pi1, idxf, rc, rlist, pairs, slist, outIdx);
  k_gather      <<<dim3(256), 256, 0, stream>>>(z, rc, rlist, zg, Ag, pbrow);
  k_rescan_pairs<<<dim3(PAIR_CAP / 256), 256, 0, stream>>>(cb, sc, rc, zg, Ag, pairs, pbrow);
  k_rescan_slow <<<dim3(64), 256, 0, stream>>>(z, cb, sc, rc, slist, idxf, outIdx);
  k_rescan_final<<<dim3(ZG_CAP / 256), 256, 0, stream>>>(rc, rlist, pbrow, idxf, outIdx);
  k_out         <<<dim3(1024), 256, 0, stream>>>(z, cb, idxf, outZ, loss_accum);
  k_finalize    <<<dim3(1), 1, 0, stream>>>(loss_accum, outLoss);
}

// Round 7
// 293.381 us; speedup vs baseline: 1.5475x; 1.2554x over previous
//
#include <hip/hip_runtime.h>
#include <hip/hip_bf16.h>
#include <float.h>
#include <math.h>

#define Bz 8
#define Dd 256
#define Tt 2048
#define Kk 8192
#define Mm (Bz*Tt)          // 16384 rows (b*T + t)

// Scorer v15: 128 rows x 256 cols, 512 thr (8 waves, 2wy x 4wx, 64x64 wave
// tiles), single-buffer LDS (As 16K + Bs 32K), v10/v14's proven 2-barrier kc
// loop -- but with SWAPPED MFMA operands: mfma(B,A) puts a z-row per lane
// (l15) and 16 codes in-register (ni,quad*4+r), making the top-2 fold 2
// shuffle steps x 4 q instead of 4 x 16 (~450 -> ~60 VALU ops). Scores are
// bit-identical (commutative dot, same accumulation chain). 2 blocks/CU =
// 16 waves/CU. Splits = 256 cols -> NSPL 32.
#define NSPL 32

#define ZG_CAP 4096
#define PAIR_CAP 131072     // candidate (row,code) pairs; expected ~6K

// Margin: covers f16 fast-pass score error + np fp32 quantization straddle
#define RESCAN_MARGIN 6e-4f

typedef __attribute__((ext_vector_type(8))) _Float16 f16x8;
typedef __attribute__((ext_vector_type(4))) float    f32x4;

// async global->LDS DMA, 16 B per lane; lds dest = wave-uniform base + lane*16
__device__ __forceinline__ void gld16(const void* g, void* l) {
  __builtin_amdgcn_global_load_lds(
      (const __attribute__((address_space(1))) void*)g,
      (__attribute__((address_space(3))) void*)l, 16, 0, 0);
}

// ---------------------------------------------------------------------------
// numpy-faithful pairwise sum of squares (blocksize-128 pairwise, 8 accums)
// ---------------------------------------------------------------------------
__device__ __forceinline__ float np_sumsq128(const float* __restrict__ x) {
  float r0 = __fmul_rn(x[0], x[0]);
  float r1 = __fmul_rn(x[1], x[1]);
  float r2 = __fmul_rn(x[2], x[2]);
  float r3 = __fmul_rn(x[3], x[3]);
  float r4 = __fmul_rn(x[4], x[4]);
  float r5 = __fmul_rn(x[5], x[5]);
  float r6 = __fmul_rn(x[6], x[6]);
  float r7 = __fmul_rn(x[7], x[7]);
  for (int i = 8; i < 128; i += 8) {
    r0 = __fadd_rn(r0, __fmul_rn(x[i+0], x[i+0]));
    r1 = __fadd_rn(r1, __fmul_rn(x[i+1], x[i+1]));
    r2 = __fadd_rn(r2, __fmul_rn(x[i+2], x[i+2]));
    r3 = __fadd_rn(r3, __fmul_rn(x[i+3], x[i+3]));
    r4 = __fadd_rn(r4, __fmul_rn(x[i+4], x[i+4]));
    r5 = __fadd_rn(r5, __fmul_rn(x[i+5], x[i+5]));
    r6 = __fadd_rn(r6, __fmul_rn(x[i+6], x[i+6]));
    r7 = __fadd_rn(r7, __fmul_rn(x[i+7], x[i+7]));
  }
  return __fadd_rn(__fadd_rn(__fadd_rn(r0, r1), __fadd_rn(r2, r3)),
                   __fadd_rn(__fadd_rn(r4, r5), __fadd_rn(r6, r7)));
}
__device__ __forceinline__ float np_sumsq256(const float* __restrict__ x) {
  return __fadd_rn(np_sumsq128(x), np_sumsq128(x + 128));
}

// ---------------------------------------------------------------------------
// k_pre: fused [cast_z | cast_cb | prep] by blockIdx range (fewer launches)
// ---------------------------------------------------------------------------
__global__ void k_pre(const float* __restrict__ z, const float* __restrict__ cb,
                      _Float16* __restrict__ Ah, _Float16* __restrict__ Bh,
                      float* __restrict__ sc,
                      double* __restrict__ loss_accum, int* __restrict__ rc) {
  const int bid = blockIdx.x;
  const int tid = threadIdx.x;
  if (bid < 1024) {
    // ---- transpose-cast z (B,D,T) f32 -> Ah (M,D) f16
    __shared__ _Float16 tile[64][64 + 8];
    const int b  = bid >> 7;
    const int dt = (bid >> 5) & 3;
    const int tt = bid & 31;
    const int d0 = dt * 64, t0 = tt * 64;
    const float* zb = z + ((size_t)b * Dd + d0) * Tt + t0;
    #pragma unroll
    for (int p = 0; p < 4; ++p) {
      const int d  = p * 16 + (tid >> 4);
      const int tl = (tid & 15) * 4;
      const float4 v = *(const float4*)(zb + (size_t)d * Tt + tl);
      tile[tl+0][d] = (_Float16)v.x;
      tile[tl+1][d] = (_Float16)v.y;
      tile[tl+2][d] = (_Float16)v.z;
      tile[tl+3][d] = (_Float16)v.w;
    }
    __syncthreads();
    const int r = tid >> 2, seg = tid & 3;
    const int m = b * Tt + t0 + r;
    int4* dst = (int4*)(Ah + (size_t)m * Dd + d0 + seg * 16);
    const int4* srcv = (const int4*)(&tile[r][seg * 16]);
    dst[0] = srcv[0];
    dst[1] = srcv[1];
  } else if (bid < 2048) {
    // ---- cast codebook f32 -> f16, prescaled by 256
    const size_t g = (size_t)(bid - 1024) * 256 + tid;
    const float4 v0 = *(const float4*)(cb + g * 8);
    const float4 v1 = *(const float4*)(cb + g * 8 + 4);
    f16x8 o;
    o[0] = (_Float16)(v0.x * 256.f); o[1] = (_Float16)(v0.y * 256.f);
    o[2] = (_Float16)(v0.z * 256.f); o[3] = (_Float16)(v0.w * 256.f);
    o[4] = (_Float16)(v1.x * 256.f); o[5] = (_Float16)(v1.y * 256.f);
    o[6] = (_Float16)(v1.z * 256.f); o[7] = (_Float16)(v1.w * 256.f);
    *(f16x8*)(Bh + g * 8) = o;
  } else {
    // ---- np-faithful codebook norms (8 lanes own np's 8 acc chains)
    if (bid == 2048 && tid == 0) {
      *loss_accum = 0.0; rc[0] = 0; rc[1] = 0; rc[2] = 0;
    }
    const int gid = (bid - 2048) * 256 + tid;
    const int lane = gid & 63;
    const int j = lane & 7, sub = lane >> 3;
    const int row = (gid >> 6) * 8 + sub;
    if (row >= Kk) return;
    const float* x = cb + (size_t)row * Dd;
    float c0 = __fmul_rn(x[j], x[j]);
    float c1 = __fmul_rn(x[128 + j], x[128 + j]);
    #pragma unroll
    for (int i = 8; i < 128; i += 8) {
      c0 = __fadd_rn(c0, __fmul_rn(x[j + i], x[j + i]));
      c1 = __fadd_rn(c1, __fmul_rn(x[128 + j + i], x[128 + j + i]));
    }
    #pragma unroll
    for (int off = 1; off <= 4; off <<= 1) {
      c0 = __fadd_rn(c0, __shfl_xor(c0, off));
      c1 = __fadd_rn(c1, __shfl_xor(c1, off));
    }
    if (j == 0) sc[row] = __fadd_rn(c0, c1);
  }
}

// ---------------------------------------------------------------------------
// f16 MFMA score pass v15 (128x256, 8 waves, swapped-operand epilogue)
// ---------------------------------------------------------------------------
__global__ __launch_bounds__(512, 4)
void k_mfma(const _Float16* __restrict__ Ah, const _Float16* __restrict__ Bh,
            const float* __restrict__ sc,
            float* __restrict__ pd1, float* __restrict__ pd2, int* __restrict__ pi1) {
  __shared__ __align__(16) _Float16 As[128 * 64];   // 16 KB, dense 128 B rows
  __shared__ __align__(16) _Float16 Bs[256 * 64];   // 32 KB
  __shared__ float mr1[512];
  __shared__ float mr2[512];
  __shared__ int   mri[512];

  const int tid  = threadIdx.x;
  const int bx   = blockIdx.x & 31;      // 32 n-tiles of 256 cols (natural order)
  const int by   = blockIdx.x >> 5;      // 128 m-tiles of 128 rows
  const int m0   = by * 128, n0 = bx * 256;
  const int w    = tid >> 6, lane = tid & 63;
  const int wy   = w >> 2, wx = w & 3;   // 2 row-bands x 4 col-quarters
  const int l15  = lane & 15, quad = lane >> 4;
  const int lhi  = lane >> 3, llo = lane & 7;   // staging roles
  const int p    = llo ^ lhi;                   // swizzled source granule
  const int sw   = l15 & 7;                     // read-side swizzle key

  f32x4 acc[4][4];
  #pragma unroll
  for (int mi = 0; mi < 4; ++mi)
    #pragma unroll
    for (int ni = 0; ni < 4; ++ni)
      acc[mi][ni] = (f32x4){0.f, 0.f, 0.f, 0.f};

  // ---- K loop: per kc stage A (128x64) + B (256x64), then 2 ks x 16 MFMA
  for (int kc = 0; kc < 4; ++kc) {
    __syncthreads();                           // prior LDS reads done
    #pragma unroll
    for (int i = 0; i < 2; ++i) {              // A: 16 chunks of 8 rows x 128 B
      const int c  = w * 2 + i;
      const int r8 = c * 8 + lhi;
      gld16(Ah + (size_t)(m0 + r8) * Dd + kc * 64 + p * 8, As + c * 512);
    }
    #pragma unroll
    for (int i = 0; i < 4; ++i) {              // B: 32 chunks
      const int c  = w * 4 + i;
      const int r8 = c * 8 + lhi;
      gld16(Bh + (size_t)(n0 + r8) * Dd + kc * 64 + p * 8, Bs + c * 512);
    }
    __syncthreads();                           // drains vmcnt -> data visible
    #pragma unroll
    for (int ks = 0; ks < 2; ++ks) {
      f16x8 af[4], bf[4];
      #pragma unroll
      for (int mi = 0; mi < 4; ++mi)
        af[mi] = *(const f16x8*)(As + (wy*64 + mi*16 + l15) * 64 + (((ks*4 + quad) ^ sw) * 8));
      #pragma unroll
      for (int ni = 0; ni < 4; ++ni)
        bf[ni] = *(const f16x8*)(Bs + (wx*64 + ni*16 + l15) * 64 + (((ks*4 + quad) ^ sw) * 8));
      // SWAPPED operands: D[code][zrow]; same dot, same chain -> bit-identical
      #pragma unroll
      for (int mi = 0; mi < 4; ++mi)
        #pragma unroll
        for (int ni = 0; ni < 4; ++ni)
          acc[mi][ni] = __builtin_amdgcn_mfma_f32_16x16x32_f16(bf[ni], af[mi], acc[mi][ni], 0, 0, 0);
    }
  }

  // ---- epilogue: lane = z-row (l15); codes in-register (ni*16 + quad*4 + r)
  float scv[4][4];
  #pragma unroll
  for (int ni = 0; ni < 4; ++ni)
    *(float4*)&scv[ni][0] = *(const float4*)(sc + n0 + wx * 64 + ni * 16 + quad * 4);

  float s1[4], s2[4]; int i1[4];
  #pragma unroll
  for (int mi = 0; mi < 4; ++mi) {
    float a1 = INFINITY, a2 = INFINITY; int ai = 0x7fffffff;
    #pragma unroll
    for (int ni = 0; ni < 4; ++ni)
      #pragma unroll
      for (int r = 0; r < 4; ++r) {            // (ni,r) ascending -> k ascending
        const float sv = fmaf(-0.0078125f, acc[mi][ni][r], scv[ni][r]);  // -2/256
        const int   k  = n0 + wx * 64 + ni * 16 + quad * 4 + r;
        if (sv < a1) { a2 = a1; a1 = sv; ai = k; }
        else if (sv < a2) a2 = sv;
      }
    s1[mi] = a1; s2[mi] = a2; i1[mi] = ai;
  }

  // fold across the 4 quad-groups (codes quad*4+r) -- 2 shuffle steps x 4 q
  #pragma unroll
  for (int off = 16; off <= 32; off <<= 1)
    #pragma unroll
    for (int q = 0; q < 4; ++q) {
      const float o1 = __shfl_xor(s1[q], off);
      const float o2 = __shfl_xor(s2[q], off);
      const int   oi = __shfl_xor(i1[q], off);
      const float n2 = fminf(fminf(s2[q], o2), fmaxf(s1[q], o1));
      if (o1 < s1[q] || (o1 == s1[q] && oi < i1[q])) { s1[q] = o1; i1[q] = oi; }
      s2[q] = n2;
    }

  // merge the 4 wx col-quarters via LDS
  if (quad == 0) {
    #pragma unroll
    for (int mi = 0; mi < 4; ++mi) {
      const int ml = wy * 64 + mi * 16 + l15;  // 0..127
      mr1[ml * 4 + wx] = s1[mi];
      mr2[ml * 4 + wx] = s2[mi];
      mri[ml * 4 + wx] = i1[mi];
    }
  }
  __syncthreads();
  if (tid < 128) {
    float a1 = INFINITY, a2 = INFINITY; int ai = 0x7fffffff;
    #pragma unroll
    for (int x = 0; x < 4; ++x) {              // wx ascending -> k ascending
      const float b1 = mr1[tid * 4 + x], b2 = mr2[tid * 4 + x];
      const int   bi = mri[tid * 4 + x];
      if (b1 < a1 || (b1 == a1 && bi < ai)) { a2 = fminf(a1, b2); a1 = b1; ai = bi; }
      else a2 = fminf(a2, b1);
    }
    const size_t o = (size_t)bx * Mm + (size_t)(m0 + tid);  // split = 256-col window
    pd1[o] = a1; pd2[o] = a2; pi1[o] = ai;
  }
}

// ---------------------------------------------------------------------------
// combine the NSPL partials per row; flag near-ties and emit candidate pairs.
// A code can only be the true argmin if its fast score <= a1 + MARGIN (same
// eps <= MARGIN/2 assumption as the gap test). Splits with s1 <= thr give
// their winner; splits with s2 <= thr (rare) need all 256 codes enumerated.
// ---------------------------------------------------------------------------
__global__ void k_combine(const float* __restrict__ pd1, const float* __restrict__ pd2,
                          const int* __restrict__ pi1, int* __restrict__ idxf,
                          int* __restrict__ rc, int* __restrict__ rlist,
                          int* __restrict__ pairs, int* __restrict__ slist,
                          float* __restrict__ outIdx) {
  const int m = blockIdx.x * blockDim.x + threadIdx.x;
  if (m >= Mm) return;
  float a1 = INFINITY, a2 = INFINITY; int ai = 0x7fffffff;
  for (int spl = 0; spl < NSPL; ++spl) {         // spl ascending -> k ascending
    const size_t o = (size_t)spl * Mm + m;
    const float b1 = pd1[o], b2 = pd2[o]; const int bi = pi1[o];
    if (b1 < a1 || (b1 == a1 && bi < ai)) { a2 = fminf(a1, b2); a1 = b1; ai = bi; }
    else a2 = fminf(a2, b1);
  }
  idxf[m]   = ai;
  outIdx[m] = (float)ai;
  if (a2 - a1 <= RESCAN_MARGIN) {
    const int p = atomicAdd(&rc[0], 1);
    if (p < ZG_CAP) {
      rlist[p] = m;
      const float thr = a1 + RESCAN_MARGIN;
      // pass 1: count candidates
      int nc = 0;
      for (int spl = 0; spl < NSPL; ++spl) {
        const size_t o = (size_t)spl * Mm + m;
        if (pd2[o] <= thr) nc += 256;
        else if (pd1[o] <= thr) ++nc;
      }
      const int base = atomicAdd(&rc[1], nc);
      if (base + nc <= PAIR_CAP) {
        int wp = base;
        for (int spl = 0; spl < NSPL; ++spl) {
          const size_t o = (size_t)spl * Mm + m;
          const float b1 = pd1[o], b2 = pd2[o];
          if (b2 <= thr) {
            const int k0 = spl * 256;
            for (int c = 0; c < 256; ++c) pairs[wp++] = (p << 13) | (k0 + c);
          } else if (b1 <= thr) {
            pairs[wp++] = (p << 13) | pi1[o];
          }
        }
      } else {
        // overflow: sentinel-fill our in-range slice (no holes), divert to slow
        for (int q = base; q < PAIR_CAP; ++q) pairs[q] = -1;
        const int s = atomicAdd(&rc[2], 1); slist[s] = m;
      }
    } else {
      // zg overflow: full slow scan for this row
      const int s = atomicAdd(&rc[2], 1); slist[s] = m;
    }
  }
}

// ---------------------------------------------------------------------------
// gather flagged rows into compact zg; np norms; init packed minima
// ---------------------------------------------------------------------------
__global__ void k_gather(const float* __restrict__ z, const int* __restrict__ rc,
                         const int* __restrict__ rlist, float* __restrict__ zg,
                         float* __restrict__ Ag, unsigned long long* __restrict__ pbrow) {
  __shared__ float zr[Dd];
  const int cnt = min(rc[0], ZG_CAP);
  for (int it = blockIdx.x; it < cnt; it += gridDim.x) {
    const int m = rlist[it];
    const int b = m / Tt, t = m & (Tt - 1);
    __syncthreads();
    zr[threadIdx.x] = z[(size_t)b * Dd * Tt + (size_t)threadIdx.x * Tt + t];
    __syncthreads();
    zg[(size_t)it * Dd + threadIdx.x] = zr[threadIdx.x];
    if (threadIdx.x == 0) { Ag[it] = np_sumsq256(zr); pbrow[it] = ~0ull; }
  }
}

// ---------------------------------------------------------------------------
// candidate-pair exact rescan: one thread per (row,code) pair; np-faithful
// fp64 dot (same segment grouping / rounding sequence as the full scan),
// packed (orderable f32, idx) atomicMin per row.
// ---------------------------------------------------------------------------
__global__ __launch_bounds__(256)
void k_rescan_pairs(const float* __restrict__ cb, const float* __restrict__ sc,
                    const int* __restrict__ rc, const float* __restrict__ zg,
                    const float* __restrict__ Ag,
                    const int* __restrict__ pairs,
                    unsigned long long* __restrict__ pbrow) {
  const int n = min(rc[1], PAIR_CAP);
  const int i = blockIdx.x * 256 + threadIdx.x;
  if (i >= n) return;
  const int pr = pairs[i];
  if (pr < 0) return;                            // overflow sentinel
  const int it = pr >> 13, k = pr & (Kk - 1);
  const float* __restrict__ zp = zg + (size_t)it * Dd;
  const float* __restrict__ cp = cb + (size_t)k * Dd;
  double M8 = 0.0;
  #pragma unroll
  for (int sg = 0; sg < 8; ++sg) {
    double a0 = 0.0, a1 = 0.0, a2 = 0.0, a3 = 0.0;
    #pragma unroll
    for (int j = 0; j < 32; j += 4) {
      const float4 c4 = *(const float4*)(cp + sg * 32 + j);
      const float4 z4 = *(const float4*)(zp + sg * 32 + j);
      a0 = fma((double)c4.x, (double)z4.x, a0);
      a1 = fma((double)c4.y, (double)z4.y, a1);
      a2 = fma((double)c4.z, (double)z4.z, a2);
      a3 = fma((double)c4.w, (double)z4.w, a3);
    }
    M8 += (a0 + a1) + (a2 + a3);
  }
  const float M  = (float)M8;
  const float t1 = __fsub_rn(Ag[it], __fmul_rn(2.0f, M));
  const float dq = __fadd_rn(t1, sc[k]);
  unsigned int fb = __float_as_uint(dq);
  fb = (fb & 0x80000000u) ? ~fb : (fb | 0x80000000u);
  const unsigned long long pack = ((unsigned long long)fb << 32) | (unsigned)k;
  atomicMin(pbrow + it, pack);
}

__global__ void k_rescan_final(const int* __restrict__ rc, const int* __restrict__ rlist,
                               const unsigned long long* __restrict__ pbrow,
                               int* __restrict__ idxf, float* __restrict__ outIdx) {
  const int cnt = min(rc[0], ZG_CAP);
  const int it = blockIdx.x * blockDim.x + threadIdx.x;
  if (it < cnt) {
    const unsigned long long pb = pbrow[it];
    if (pb != ~0ull) {                           // untouched => slow-path row
      const int idx = (int)(unsigned)(pb & 0xFFFFFFFFull);
      const int m = rlist[it];
      idxf[m] = idx; outIdx[m] = (float)idx;
    }
  }
}

// overflow fallback: normally 0 iterations
__global__ void k_rescan_slow(const float* __restrict__ z, const float* __restrict__ cb,
                              const float* __restrict__ sc,
                              const int* __restrict__ rc, const int* __restrict__ slist,
                              int* __restrict__ idxf, float* __restrict__ outIdx) {
  __shared__ float zrow[Dd];
  __shared__ float Ash;
  __shared__ float sval[256];
  __shared__ int   sidx[256];
  const int tid = threadIdx.x;
  const int cnt = rc[2];
  for (int it = blockIdx.x; it < cnt; it += gridDim.x) {
    const int m = slist[it];
    const int b = m / Tt, t = m & (Tt - 1);
    __syncthreads();
    zrow[tid] = z[(size_t)b * Dd * Tt + (size_t)tid * Tt + t];
    __syncthreads();
    if (tid == 0) Ash = np_sumsq256(zrow);
    __syncthreads();
    const float A = Ash;
    float best = INFINITY; int bi = 0x7fffffff;
    for (int k = tid; k < Kk; k += 256) {
      const float* cr = cb + (size_t)k * Dd;
      double a0 = 0.0, a1 = 0.0, a2 = 0.0, a3 = 0.0;
      for (int d = 0; d < Dd; d += 4) {
        const float4 c4 = *(const float4*)(cr + d);
        a0 = fma((double)c4.x, (double)zrow[d+0], a0);
        a1 = fma((double)c4.y, (double)zrow[d+1], a1);
        a2 = fma((double)c4.z, (double)zrow[d+2], a2);
        a3 = fma((double)c4.w, (double)zrow[d+3], a3);
      }
      const float M  = (float)((a0 + a1) + (a2 + a3));
      const float t1 = __fsub_rn(A, __fmul_rn(2.0f, M));
      const float dq = __fadd_rn(t1, sc[k]);
      if (dq < best) { best = dq; bi = k; }
    }
    sval[tid] = best; sidx[tid] = bi;
    __syncthreads();
    for (int off = 128; off; off >>= 1) {
      if (tid < off) {
        if (sval[tid+off] < sval[tid] ||
            (sval[tid+off] == sval[tid] && sidx[tid+off] < sidx[tid])) {
          sval[tid] = sval[tid+off]; sidx[tid] = sidx[tid+off];
        }
      }
      __syncthreads();
    }
    if (tid == 0) { idxf[m] = sidx[0]; outIdx[m] = (float)sidx[0]; }
    __syncthreads();
  }
}

// ---------------------------------------------------------------------------
// fused gather + transpose + STE + loss: out[b][d][t] = z + (cb[idx] - z)
// ---------------------------------------------------------------------------
__global__ void k_out(const float* __restrict__ z, const float* __restrict__ cb,
                      const int* __restrict__ idxf,
                      float* __restrict__ outZ, double* __restrict__ loss_accum) {
  __shared__ float tile[64][65];          // [d][t]
  const int tid = threadIdx.x;
  const int bidx = blockIdx.x;            // 8 * 4 * 32 = 1024
  const int b  = bidx >> 7;
  const int dt = (bidx >> 5) & 3;
  const int tt = bidx & 31;
  const int d0 = dt * 64, t0 = tt * 64;
  {
    const int r = tid >> 2, seg = tid & 3;
    const int idx = idxf[b * Tt + t0 + r];
    const float* src = cb + (size_t)idx * Dd + d0 + seg * 16;
    #pragma unroll
    for (int q4 = 0; q4 < 4; ++q4) {
      const float4 v = *(const float4*)(src + q4 * 4);
      tile[seg * 16 + q4 * 4 + 0][r] = v.x;
      tile[seg * 16 + q4 * 4 + 1][r] = v.y;
      tile[seg * 16 + q4 * 4 + 2][r] = v.z;
      tile[seg * 16 + q4 * 4 + 3][r] = v.w;
    }
  }
  __syncthreads();
  const float* zbase = z + ((size_t)b * Dd + d0) * Tt + t0;
  float*       obase = outZ + ((size_t)b * Dd + d0) * Tt + t0;
  double ls = 0.0;
  #pragma unroll
  for (int p = 0; p < 4; ++p) {
    const int d  = p * 16 + (tid >> 4);
    const int t4 = (tid & 15) * 4;
    const float4 zv = *(const float4*)(zbase + (size_t)d * Tt + t4);
    const float q0 = tile[d][t4+0], q1 = tile[d][t4+1];
    const float q2 = tile[d][t4+2], q3 = tile[d][t4+3];
    const float r0 = q0 - zv.x, r1 = q1 - zv.y, r2 = q2 - zv.z, r3 = q3 - zv.w;
    float4 o;
    o.x = zv.x + r0; o.y = zv.y + r1; o.z = zv.z + r2; o.w = zv.w + r3;
    *(float4*)(obase + (size_t)d * Tt + t4) = o;
    ls += (double)r0*r0 + (double)r1*r1 + (double)r2*r2 + (double)r3*r3;
  }
  #pragma unroll
  for (int off = 32; off; off >>= 1) ls += __shfl_down(ls, off);
  if ((tid & 63) == 0) atomicAdd(loss_accum, ls);
}

__global__ void k_finalize(const double* __restrict__ loss_accum, float* __restrict__ outLoss) {
  const double mean = *loss_accum / (double)((size_t)Bz * Dd * Tt);
  *outLoss = (float)(mean + 0.1 * mean);
}

// ---------------------------------------------------------------------------
extern "C" void kernel_launch(void* const* d_in, const int* in_sizes, int n_in,
                              void* d_out, int out_size, void* d_ws, size_t ws_size,
                              hipStream_t stream) {
  (void)in_sizes; (void)n_in; (void)out_size; (void)ws_size;
  const float* z  = (const float*)d_in[0];   // (B, D, T) fp32
  const float* cb = (const float*)d_in[1];   // (K, D)    fp32

  float* outZ    = (float*)d_out;
  float* outIdx  = outZ + (size_t)Bz * Dd * Tt;
  float* outLoss = outIdx + Mm;

  char* w = (char*)d_ws;
  double*    loss_accum = (double*)w;    w += 16;
  int*       rc         = (int*)w;       w += 16;   // [0]=rows [1]=pairs [2]=slow
  int*       rlist      = (int*)w;       w += sizeof(int)   * Mm;
  int*       slist      = (int*)w;       w += sizeof(int)   * Mm;
  int*       idxf       = (int*)w;       w += sizeof(int)   * Mm;
  float*     sc         = (float*)w;     w += sizeof(float) * Kk;
  _Float16*  Ah         = (_Float16*)w;  w += sizeof(_Float16) * (size_t)Mm * Dd;
  _Float16*  Bh         = (_Float16*)w;  w += sizeof(_Float16) * (size_t)Kk * Dd;
  float*     zg         = (float*)w;     w += sizeof(float) * (size_t)ZG_CAP * Dd;
  float*     Ag         = (float*)w;     w += sizeof(float) * ZG_CAP;
  unsigned long long* pbrow = (unsigned long long*)w; w += sizeof(unsigned long long) * ZG_CAP;
  int*       pairs      = (int*)w;       w += sizeof(int) * PAIR_CAP;
  float*     pd1        = (float*)w;     w += sizeof(float) * (size_t)NSPL * Mm;
  float*     pd2        = (float*)w;     w += sizeof(float) * (size_t)NSPL * Mm;
  int*       pi1        = (int*)w;       /* total ~25 MB */

  k_pre         <<<dim3(2304), 256, 0, stream>>>(z, cb, Ah, Bh, sc, loss_accum, rc);
  k_mfma        <<<dim3((Mm / 128) * (Kk / 256)), 512, 0, stream>>>(Ah, Bh, sc, pd1, pd2, pi1);
  k_combine     <<<dim3(Mm / 256), 256, 0, stream>>>(pd1, pd2, pi1, idxf, rc, rlist, pairs, slist, outIdx);
  k_gather      <<<dim3(256), 256, 0, stream>>>(z, rc, rlist, zg, Ag, pbrow);
  k_rescan_pairs<<<dim3(PAIR_CAP / 256), 256, 0, stream>>>(cb, sc, rc, zg, Ag, pairs, pbrow);
  k_rescan_slow <<<dim3(64), 256, 0, stream>>>(z, cb, sc, rc, slist, idxf, outIdx);
  k_rescan_final<<<dim3(ZG_CAP / 256), 256, 0, stream>>>(rc, rlist, pbrow, idxf, outIdx);
  k_out         <<<dim3(1024), 256, 0, stream>>>(z, cb, idxf, outZ, loss_accum);
  k_finalize    <<<dim3(1), 1, 0, stream>>>(loss_accum, outLoss);
}